// Round 4
// baseline (7005.726 us; speedup 1.0000x reference)
//
#include <hip/hip_runtime.h>

#define T_SEQ  2048
#define HID    4096
#define NQH    32
#define NKVH   8
#define HDIM   128

// ---------------------------------------------------------------- fp32 LDS-tiled GEMM
// C[M,N] = A[M,K] * W[K,N], all fp32 row-major, f32 accumulate
__global__ __launch_bounds__(256) void gemm_s(const float* __restrict__ A,
                                              const float* __restrict__ W,
                                              float* __restrict__ C,
                                              int M, int N, int K) {
  __shared__ float As[16][64];  // [k][m]
  __shared__ float Bs[16][64];  // [k][n]
  const int tid = threadIdx.x;
  const int m0 = blockIdx.y * 64, n0 = blockIdx.x * 64;
  const int ty = tid >> 4, tx = tid & 15;
  const int ar = tid >> 2, ak = (tid & 3) * 4;   // A: row m0+ar, k kt+ak..+3
  const int br = tid >> 4, bc = (tid & 15) * 4;  // B: k kt+br, col n0+bc..+3

  float acc[4][4];
#pragma unroll
  for (int r = 0; r < 4; r++)
#pragma unroll
    for (int c = 0; c < 4; c++) acc[r][c] = 0.f;

  for (int kt = 0; kt < K; kt += 16) {
    __syncthreads();
    {
      float4 f = *(const float4*)(A + (long long)(m0 + ar) * K + kt + ak);
      As[ak + 0][ar] = f.x; As[ak + 1][ar] = f.y;
      As[ak + 2][ar] = f.z; As[ak + 3][ar] = f.w;
    }
    {
      float4 g = *(const float4*)(W + (long long)(kt + br) * N + n0 + bc);
      Bs[br][bc + 0] = g.x; Bs[br][bc + 1] = g.y;
      Bs[br][bc + 2] = g.z; Bs[br][bc + 3] = g.w;
    }
    __syncthreads();
#pragma unroll
    for (int kk = 0; kk < 16; kk++) {
      float4 a = *(const float4*)&As[kk][ty * 4];
      float4 b = *(const float4*)&Bs[kk][tx * 4];
      float av[4] = {a.x, a.y, a.z, a.w};
      float bv[4] = {b.x, b.y, b.z, b.w};
#pragma unroll
      for (int r = 0; r < 4; r++)
#pragma unroll
        for (int c = 0; c < 4; c++) acc[r][c] += av[r] * bv[c];
    }
  }

#pragma unroll
  for (int r = 0; r < 4; r++)
#pragma unroll
    for (int c = 0; c < 4; c++)
      C[(long long)(m0 + ty * 4 + r) * N + n0 + tx * 4 + c] = acc[r][c];
}

// ---------------------------------------------------------------- RoPE v2 (neox), fp64 angles
// grid (T, H), block 64: thread d handles pair (d, d+64) of row (t, h)
__global__ void rope_v2(float* __restrict__ buf,
                        const int* __restrict__ positions, int H) {
  const int t = blockIdx.x, h = blockIdx.y, d = threadIdx.x;
  double inv = exp2(-(double)d * 0.20762050593046014);  // 10000^(-d/64)
  double ang = (double)positions[t] * inv;
  double c = cos(ang), s = sin(ang);
  float* row = buf + (size_t)t * (H * HDIM) + (size_t)h * HDIM;
  float x1 = row[d], x2 = row[d + 64];
  row[d]      = (float)((double)x1 * c - (double)x2 * s);
  row[d + 64] = (float)((double)x2 * c + (double)x1 * s);
}

// ---------------------------------------------------------------- simple attention, fp32
// one wave per (head, q-row); lane holds dims 2*lane, 2*lane+1; online softmax in f32
__global__ __launch_bounds__(256) void attn_simple(const float* __restrict__ qb,
                                                   const float* __restrict__ kb,
                                                   const float* __restrict__ vb,
                                                   float* __restrict__ ab) {
  const int w = threadIdx.x >> 6, lane = threadIdx.x & 63;
  const int gid = blockIdx.x * 4 + w;        // 0 .. T*NQH-1
  const int h = gid >> 11;                   // gid / T_SEQ
  const int q = gid & (T_SEQ - 1);
  const int kvh = h >> 2;

  const float2 qv = *(const float2*)(qb + (long long)q * (NQH * HDIM) + h * HDIM + lane * 2);
  const float sc = 0.08838834764831845f;
  float q0 = qv.x * sc, q1 = qv.y * sc;

  float m = -3e38f, lsum = 0.f, o0 = 0.f, o1 = 0.f;
  const float* kp = kb + kvh * HDIM + lane * 2;
  const float* vp = vb + kvh * HDIM + lane * 2;

  for (int k = 0; k <= q; k++) {
    long long off = (long long)k * (NKVH * HDIM);
    float2 kv = *(const float2*)(kp + off);
    float s = q0 * kv.x + q1 * kv.y;
#pragma unroll
    for (int o = 32; o >= 1; o >>= 1) s += __shfl_xor(s, o, 64);
    float mn = fmaxf(m, s);
    float c = __expf(m - mn);
    float p = __expf(s - mn);
    m = mn;
    lsum = lsum * c + p;
    float2 vv = *(const float2*)(vp + off);
    o0 = o0 * c + p * vv.x;
    o1 = o1 * c + p * vv.y;
  }

  float* op = ab + (long long)q * (NQH * HDIM) + h * HDIM + lane * 2;
  op[0] = o0 / lsum;
  op[1] = o1 / lsum;
}

// ---------------------------------------------------------------- launch
extern "C" void kernel_launch(void* const* d_in, const int* in_sizes, int n_in,
                              void* d_out, int out_size, void* d_ws, size_t ws_size,
                              hipStream_t stream) {
  const int*   positions = (const int*)d_in[0];
  const float* hs = (const float*)d_in[1];
  const float* wq = (const float*)d_in[2];
  const float* wk = (const float*)d_in[3];
  const float* wv = (const float*)d_in[4];
  const float* wo = (const float*)d_in[5];
  float* out = (float*)d_out;

  // fp32 workspace: qb 33.6MB + kb 8.4 + vb 8.4 + ab 33.6 = 84 MB
  const size_t need = ((size_t)T_SEQ * NQH * HDIM + (size_t)T_SEQ * NKVH * HDIM * 2 +
                       (size_t)T_SEQ * NQH * HDIM) * 4;
  if (ws_size < need) return;  // leaves d_out zero: absmax 4.625 signature

  char* p = (char*)d_ws;
  float* qb = (float*)p; p += (size_t)T_SEQ * NQH * HDIM * 4;
  float* kb = (float*)p; p += (size_t)T_SEQ * NKVH * HDIM * 4;
  float* vb = (float*)p; p += (size_t)T_SEQ * NKVH * HDIM * 4;
  float* ab = (float*)p; p += (size_t)T_SEQ * NQH * HDIM * 4;

  gemm_s<<<dim3((NQH * HDIM) / 64, T_SEQ / 64), 256, 0, stream>>>(hs, wq, qb, T_SEQ, NQH * HDIM, HID);
  gemm_s<<<dim3((NKVH * HDIM) / 64, T_SEQ / 64), 256, 0, stream>>>(hs, wk, kb, T_SEQ, NKVH * HDIM, HID);
  gemm_s<<<dim3((NKVH * HDIM) / 64, T_SEQ / 64), 256, 0, stream>>>(hs, wv, vb, T_SEQ, NKVH * HDIM, HID);

  rope_v2<<<dim3(T_SEQ, NQH), 64, 0, stream>>>(qb, positions, NQH);
  rope_v2<<<dim3(T_SEQ, NKVH), 64, 0, stream>>>(kb, positions, NKVH);

  attn_simple<<<(T_SEQ * NQH) / 4, 256, 0, stream>>>(qb, kb, vb, ab);

  gemm_s<<<dim3(HID / 64, T_SEQ / 64), 256, 0, stream>>>(ab, wo, out, T_SEQ, HID, NQH * HDIM);
}

// Round 5
// 1284.133 us; speedup vs baseline: 5.4556x; 5.4556x over previous
//
#include <hip/hip_runtime.h>

#define T_SEQ  2048
#define HID    4096
#define NQH    32
#define NKVH   8
#define HDIM   128

typedef float  f32x4  __attribute__((ext_vector_type(4)));
typedef __bf16 bf16x8 __attribute__((ext_vector_type(8)));

__device__ __forceinline__ float bf2f(unsigned short u) {
  union { unsigned int i; float f; } v; v.i = ((unsigned int)u) << 16; return v.f;
}
__device__ __forceinline__ unsigned short f2bf(float f) {
  union { float f; unsigned int i; } v; v.f = f;
  unsigned int r = v.i + 0x7fffu + ((v.i >> 16) & 1u);
  return (unsigned short)(r >> 16);
}

__device__ __forceinline__ f32x4 mfma_bf16(bf16x8 a, bf16x8 b, f32x4 c) {
  return __builtin_amdgcn_mfma_f32_16x16x32_bf16(a, b, c, 0, 0, 0);
}

#define GLOAD16(g, l)                                              \
  __builtin_amdgcn_global_load_lds(                                \
      (const __attribute__((address_space(1))) void*)(g),          \
      (__attribute__((address_space(3))) void*)(l), 16, 0, 0)

// ---------------------------------------------------------------- convert
__global__ void conv_f32_bf16(const float* __restrict__ in,
                              unsigned short* __restrict__ out) {
  long long i = ((long long)blockIdx.x * 256 + threadIdx.x) * 4;
  float4 v = *(const float4*)(in + i);
  union { unsigned short u[4]; uint2 p; } o;
  o.u[0] = f2bf(v.x); o.u[1] = f2bf(v.y); o.u[2] = f2bf(v.z); o.u[3] = f2bf(v.w);
  *(uint2*)(out + i) = o.p;
}

// ---------------------------------------------------------------- GEMM
// C[M,N] = A[M,K](bf16 row-major) * W[K,N](fp32 row-major)
// B-tile transposed+converted during LDS staging: Bs[n][k] bf16.
// EPI: 0 = bf16 row-major out, 1 = bf16 transposed out (C[n][m]), 2 = fp32 row-major out
template <int EPI>
__global__ __launch_bounds__(256) void gemm_fb(const unsigned short* __restrict__ A,
                                               const float* __restrict__ W,
                                               void* __restrict__ Cv,
                                               int M, int N, int K) {
  __shared__ unsigned short As[128 * 32];
  __shared__ unsigned short Bs[128 * 32];
  const int t = threadIdx.x;
  const int lane = t & 63, w = t >> 6;
  const int wr = w >> 1, wc = w & 1;
  const int l15 = lane & 15, lg = lane >> 4;
  const int m0 = blockIdx.y * 128, n0 = blockIdx.x * 128;

  f32x4 acc[4][4];
#pragma unroll
  for (int i = 0; i < 4; i++)
#pragma unroll
    for (int j = 0; j < 4; j++) acc[i][j] = (f32x4){0.f, 0.f, 0.f, 0.f};

  const int c0 = t, c1 = t + 256;      // A-tile 16B chunks: row = c>>2, sub = c&3
  const int bk = t >> 3;               // B: k-row 0..31
  const int bn = (t & 7) * 16;         // B: n-chunk 0..112

  for (int kt = 0; kt < K; kt += 32) {
    __syncthreads();
    GLOAD16(A + (long long)(m0 + (c0 >> 2)) * K + kt + (c0 & 3) * 8,
            (char*)As + (w * 64) * 16);
    GLOAD16(A + (long long)(m0 + (c1 >> 2)) * K + kt + (c1 & 3) * 8,
            (char*)As + (w * 64 + 256) * 16);
    {
      const float* src = W + (long long)(kt + bk) * N + n0 + bn;
      float4 f0 = ((const float4*)src)[0];
      float4 f1 = ((const float4*)src)[1];
      float4 f2 = ((const float4*)src)[2];
      float4 f3 = ((const float4*)src)[3];
      unsigned short* dst = Bs + bk;
      dst[(bn + 0) * 32]  = f2bf(f0.x); dst[(bn + 1) * 32]  = f2bf(f0.y);
      dst[(bn + 2) * 32]  = f2bf(f0.z); dst[(bn + 3) * 32]  = f2bf(f0.w);
      dst[(bn + 4) * 32]  = f2bf(f1.x); dst[(bn + 5) * 32]  = f2bf(f1.y);
      dst[(bn + 6) * 32]  = f2bf(f1.z); dst[(bn + 7) * 32]  = f2bf(f1.w);
      dst[(bn + 8) * 32]  = f2bf(f2.x); dst[(bn + 9) * 32]  = f2bf(f2.y);
      dst[(bn + 10) * 32] = f2bf(f2.z); dst[(bn + 11) * 32] = f2bf(f2.w);
      dst[(bn + 12) * 32] = f2bf(f3.x); dst[(bn + 13) * 32] = f2bf(f3.y);
      dst[(bn + 14) * 32] = f2bf(f3.z); dst[(bn + 15) * 32] = f2bf(f3.w);
    }
    __syncthreads();

    bf16x8 af[4], bfr[4];
#pragma unroll
    for (int mi = 0; mi < 4; mi++)
      af[mi] = *(const bf16x8*)(As + (wr * 64 + mi * 16 + l15) * 32 + lg * 8);
#pragma unroll
    for (int ni = 0; ni < 4; ni++)
      bfr[ni] = *(const bf16x8*)(Bs + (wc * 64 + ni * 16 + l15) * 32 + lg * 8);
#pragma unroll
    for (int mi = 0; mi < 4; mi++)
#pragma unroll
      for (int ni = 0; ni < 4; ni++)
        acc[mi][ni] = mfma_bf16(af[mi], bfr[ni], acc[mi][ni]);
  }

  const int row0 = m0 + wr * 64, col0 = n0 + wc * 64;
#pragma unroll
  for (int mi = 0; mi < 4; mi++)
#pragma unroll
    for (int ni = 0; ni < 4; ni++) {
      int rbase = row0 + mi * 16 + lg * 4;
      int col = col0 + ni * 16 + l15;
#pragma unroll
      for (int r = 0; r < 4; r++) {
        float v = acc[mi][ni][r];
        if (EPI == 0)
          ((unsigned short*)Cv)[(long long)(rbase + r) * N + col] = f2bf(v);
        else if (EPI == 1)
          ((unsigned short*)Cv)[(long long)col * M + (rbase + r)] = f2bf(v);
        else
          ((float*)Cv)[(long long)(rbase + r) * N + col] = v;
      }
    }
}

// ---------------------------------------------------------------- RoPE (neox, fp64 angles) on bf16 [T][H*128]
// block 256 = 4 waves; wave handles one (t,h) row; lane d in 0..63
__global__ void rope_bf(unsigned short* __restrict__ buf,
                        const int* __restrict__ positions, int H) {
  const int w = threadIdx.x >> 6, d = threadIdx.x & 63;
  const int gid = blockIdx.x * 4 + w;  // t*H + h
  const int h = gid % H, t = gid / H;
  double inv = exp2(-(double)d * 0.20762050593046014);  // 10000^(-d/64)
  double ang = (double)positions[t] * inv;
  double c = cos(ang), s = sin(ang);
  unsigned short* row = buf + (size_t)t * (H * HDIM) + (size_t)h * HDIM;
  float x1 = bf2f(row[d]), x2 = bf2f(row[d + 64]);
  row[d]      = f2bf((float)((double)x1 * c - (double)x2 * s));
  row[d + 64] = f2bf((float)((double)x2 * c + (double)x1 * s));
}

// ---------------------------------------------------------------- flash attention
// grid: (T/64, NQH); block 256 = 4 waves x 16 q-rows; KBLK=32
__global__ __launch_bounds__(256) void attn_kernel(const unsigned short* __restrict__ qb,
                                                   const unsigned short* __restrict__ kb,
                                                   const unsigned short* __restrict__ vt,
                                                   unsigned short* __restrict__ ab) {
  __shared__ unsigned short Qs[64 * 128];
  __shared__ unsigned short Ks[32 * 128];
  __shared__ unsigned short Vs[128 * 32];
  __shared__ unsigned short Ps[4][16 * 32];

  const int qblk = gridDim.x - 1 - blockIdx.x;  // long blocks first
  const int h = blockIdx.y;
  const int kvh = h >> 2;
  const int q0 = qblk * 64;
  const int t = threadIdx.x, lane = t & 63, w = t >> 6;
  const int l15 = lane & 15, lg = lane >> 4;

  // stage Q tile (64 x 128)
#pragma unroll
  for (int s = 0; s < 4; s++) {
    int c = t + s * 256;
    GLOAD16(qb + (long long)(q0 + (c >> 4)) * (NQH * HDIM) + h * HDIM + (c & 15) * 8,
            (char*)Qs + (w * 64 + s * 256) * 16);
  }

  f32x4 accO[8];
#pragma unroll
  for (int db = 0; db < 8; db++) accO[db] = (f32x4){0.f, 0.f, 0.f, 0.f};
  float mrun[4] = {-3e38f, -3e38f, -3e38f, -3e38f};
  float lrun[4] = {0.f, 0.f, 0.f, 0.f};

  const int nkt = (q0 + 64) >> 5;
  for (int kt = 0; kt < nkt; kt++) {
    __syncthreads();
#pragma unroll
    for (int s = 0; s < 2; s++) {
      int c = t + s * 256;
      GLOAD16(kb + (long long)(kt * 32 + (c >> 4)) * (NKVH * HDIM) + kvh * HDIM + (c & 15) * 8,
              (char*)Ks + (w * 64 + s * 256) * 16);
    }
#pragma unroll
    for (int s = 0; s < 2; s++) {
      int c = t + s * 256;
      GLOAD16(vt + (long long)(kvh * HDIM + (c >> 2)) * T_SEQ + kt * 32 + (c & 3) * 8,
              (char*)Vs + (w * 64 + s * 256) * 16);
    }
    __syncthreads();

    // S = Q K^T : wave's 16 q-rows x 32 k-cols
    f32x4 accS[2];
    accS[0] = (f32x4){0.f, 0.f, 0.f, 0.f};
    accS[1] = (f32x4){0.f, 0.f, 0.f, 0.f};
#pragma unroll
    for (int kk = 0; kk < 4; kk++) {
      bf16x8 a = *(const bf16x8*)(Qs + (w * 16 + l15) * 128 + kk * 32 + lg * 8);
#pragma unroll
      for (int kc = 0; kc < 2; kc++) {
        bf16x8 b = *(const bf16x8*)(Ks + (kc * 16 + l15) * 128 + kk * 32 + lg * 8);
        accS[kc] = mfma_bf16(a, b, accS[kc]);
      }
    }

    const float sc = 0.08838834764831845f;
    const int qrow = q0 + w * 16 + lg * 4;  // + r
    float pm[2][4];
#pragma unroll
    for (int kc = 0; kc < 2; kc++) {
      int kcol = kt * 32 + kc * 16 + l15;
#pragma unroll
      for (int r = 0; r < 4; r++) {
        float sv = accS[kc][r] * sc;
        pm[kc][r] = (kcol > qrow + r) ? -3e38f : sv;
      }
    }
    float rm[4];
#pragma unroll
    for (int r = 0; r < 4; r++) rm[r] = fmaxf(pm[0][r], pm[1][r]);
#pragma unroll
    for (int off = 1; off < 16; off <<= 1)
#pragma unroll
      for (int r = 0; r < 4; r++) rm[r] = fmaxf(rm[r], __shfl_xor(rm[r], off, 64));
    float corr[4];
#pragma unroll
    for (int r = 0; r < 4; r++) {
      float mn = fmaxf(mrun[r], rm[r]);
      corr[r] = __expf(mrun[r] - mn);
      mrun[r] = mn;
    }
    float rs[4] = {0.f, 0.f, 0.f, 0.f};
    unsigned short pb[2][4];
#pragma unroll
    for (int kc = 0; kc < 2; kc++)
#pragma unroll
      for (int r = 0; r < 4; r++) {
        float p = __expf(pm[kc][r] - mrun[r]);
        rs[r] += p;
        pb[kc][r] = f2bf(p);
      }
#pragma unroll
    for (int off = 1; off < 16; off <<= 1)
#pragma unroll
      for (int r = 0; r < 4; r++) rs[r] += __shfl_xor(rs[r], off, 64);
#pragma unroll
    for (int r = 0; r < 4; r++) lrun[r] = lrun[r] * corr[r] + rs[r];
#pragma unroll
    for (int db = 0; db < 8; db++)
#pragma unroll
      for (int r = 0; r < 4; r++) accO[db][r] *= corr[r];

    unsigned short* Pw = Ps[w];
#pragma unroll
    for (int kc = 0; kc < 2; kc++)
#pragma unroll
      for (int r = 0; r < 4; r++)
        Pw[(lg * 4 + r) * 32 + kc * 16 + l15] = pb[kc][r];
    asm volatile("s_waitcnt lgkmcnt(0)" ::: "memory");

    bf16x8 pa = *(const bf16x8*)(Pw + l15 * 32 + lg * 8);
#pragma unroll
    for (int db = 0; db < 8; db++) {
      bf16x8 b = *(const bf16x8*)(Vs + (db * 16 + l15) * 32 + lg * 8);
      accO[db] = mfma_bf16(pa, b, accO[db]);
    }
  }

#pragma unroll
  for (int db = 0; db < 8; db++)
#pragma unroll
    for (int r = 0; r < 4; r++) {
      int qr = q0 + w * 16 + lg * 4 + r;
      int col = h * HDIM + db * 16 + l15;
      ab[(long long)qr * (NQH * HDIM) + col] = f2bf(accO[db][r] / lrun[r]);
    }
}

// ---------------------------------------------------------------- launch
extern "C" void kernel_launch(void* const* d_in, const int* in_sizes, int n_in,
                              void* d_out, int out_size, void* d_ws, size_t ws_size,
                              hipStream_t stream) {
  const int*   positions = (const int*)d_in[0];
  const float* hs = (const float*)d_in[1];
  const float* wq = (const float*)d_in[2];
  const float* wk = (const float*)d_in[3];
  const float* wv = (const float*)d_in[4];
  const float* wo = (const float*)d_in[5];
  float* out = (float*)d_out;

  // workspace: 56 MB
  const size_t need = (size_t)(16 + 16 + 4 + 4 + 16) * 1024 * 1024;
  if (ws_size < need) return;  // absmax 4.625 signature

  char* p = (char*)d_ws;
  unsigned short* hb  = (unsigned short*)p; p += (size_t)T_SEQ * HID * 2;           // 16 MB
  unsigned short* qb  = (unsigned short*)p; p += (size_t)T_SEQ * NQH * HDIM * 2;    // 16 MB
  unsigned short* kb  = (unsigned short*)p; p += (size_t)T_SEQ * NKVH * HDIM * 2;   //  4 MB
  unsigned short* vtb = (unsigned short*)p; p += (size_t)NKVH * HDIM * T_SEQ * 2;   //  4 MB
  unsigned short* ab  = (unsigned short*)p; p += (size_t)T_SEQ * NQH * HDIM * 2;    // 16 MB

  conv_f32_bf16<<<(T_SEQ * HID) / 1024, 256, 0, stream>>>(hs, hb);

  gemm_fb<0><<<dim3((NQH * HDIM) / 128, T_SEQ / 128), 256, 0, stream>>>(hb, wq, qb, T_SEQ, NQH * HDIM, HID);
  gemm_fb<0><<<dim3((NKVH * HDIM) / 128, T_SEQ / 128), 256, 0, stream>>>(hb, wk, kb, T_SEQ, NKVH * HDIM, HID);
  gemm_fb<1><<<dim3((NKVH * HDIM) / 128, T_SEQ / 128), 256, 0, stream>>>(hb, wv, vtb, T_SEQ, NKVH * HDIM, HID);

  rope_bf<<<(T_SEQ * NQH) / 4, 256, 0, stream>>>(qb, positions, NQH);
  rope_bf<<<(T_SEQ * NKVH) / 4, 256, 0, stream>>>(kb, positions, NKVH);

  attn_kernel<<<dim3(T_SEQ / 64, NQH), 256, 0, stream>>>(qb, kb, vtb, ab);

  gemm_fb<2><<<dim3(HID / 128, T_SEQ / 128), 256, 0, stream>>>(ab, wo, out, T_SEQ, HID, NQH * HDIM);
}

// Round 6
// 636.471 us; speedup vs baseline: 11.0071x; 2.0176x over previous
//
#include <hip/hip_runtime.h>

#define T_SEQ  2048
#define HID    4096
#define NQH    32
#define NKVH   8
#define HDIM   128

typedef float  f32x4  __attribute__((ext_vector_type(4)));
typedef __bf16 bf16x8 __attribute__((ext_vector_type(8)));

__device__ __forceinline__ float bf2f(unsigned short u) {
  union { unsigned int i; float f; } v; v.i = ((unsigned int)u) << 16; return v.f;
}
__device__ __forceinline__ unsigned short f2bf(float f) {
  union { float f; unsigned int i; } v; v.f = f;
  unsigned int r = v.i + 0x7fffu + ((v.i >> 16) & 1u);
  return (unsigned short)(r >> 16);
}

__device__ __forceinline__ f32x4 mfma_bf16(bf16x8 a, bf16x8 b, f32x4 c) {
  return __builtin_amdgcn_mfma_f32_16x16x32_bf16(a, b, c, 0, 0, 0);
}

#define GLOAD16(g, l)                                              \
  __builtin_amdgcn_global_load_lds(                                \
      (const __attribute__((address_space(1))) void*)(g),          \
      (__attribute__((address_space(3))) void*)(l), 16, 0, 0)

// ---------------------------------------------------------------- convert
__global__ void conv_f32_bf16(const float* __restrict__ in,
                              unsigned short* __restrict__ out) {
  long long i = ((long long)blockIdx.x * 256 + threadIdx.x) * 4;
  float4 v = *(const float4*)(in + i);
  union { unsigned short u[4]; uint2 p; } o;
  o.u[0] = f2bf(v.x); o.u[1] = f2bf(v.y); o.u[2] = f2bf(v.z); o.u[3] = f2bf(v.w);
  *(uint2*)(out + i) = o.p;
}

// W[K][N] fp32  ->  Wt[N][K] bf16
__global__ void transpose_conv(const float* __restrict__ W,
                               unsigned short* __restrict__ Wt, int K, int N) {
  __shared__ float tile[32][33];
  int n0 = blockIdx.x * 32, k0 = blockIdx.y * 32;
  int tx = threadIdx.x & 31, ty = threadIdx.x >> 5;  // ty 0..7
#pragma unroll
  for (int r = 0; r < 32; r += 8)
    tile[ty + r][tx] = W[(long long)(k0 + ty + r) * N + n0 + tx];
  __syncthreads();
#pragma unroll
  for (int r = 0; r < 32; r += 8)
    Wt[(long long)(n0 + ty + r) * K + k0 + tx] = f2bf(tile[tx][ty + r]);
}

// ---------------------------------------------------------------- GEMM (m97 structure)
// C[M,N] = A[M,K](bf16,row-major) * Bt[N,K](bf16,row-major)^T
// EPI: 0 = bf16 row-major out, 1 = bf16 transposed out (C[n][m]), 2 = fp32 row-major out
template <int EPI>
__global__ __launch_bounds__(256) void gemm_bt(const unsigned short* __restrict__ A,
                                               const unsigned short* __restrict__ Bt,
                                               void* __restrict__ Cv,
                                               int M, int N, int K) {
  __shared__ unsigned short As[128 * 32];
  __shared__ unsigned short Bs[128 * 32];
  const int t = threadIdx.x;
  const int lane = t & 63, w = t >> 6;
  const int wr = w >> 1, wc = w & 1;
  const int l15 = lane & 15, lg = lane >> 4;
  const int m0 = blockIdx.y * 128, n0 = blockIdx.x * 128;

  f32x4 acc[4][4];
#pragma unroll
  for (int i = 0; i < 4; i++)
#pragma unroll
    for (int j = 0; j < 4; j++) acc[i][j] = (f32x4){0.f, 0.f, 0.f, 0.f};

  const int c0 = t, c1 = t + 256;  // 16B chunks (row = c>>2, sub = c&3)

  for (int kt = 0; kt < K; kt += 32) {
    __syncthreads();
    GLOAD16(A + (long long)(m0 + (c0 >> 2)) * K + kt + (c0 & 3) * 8,
            (char*)As + (w * 64) * 16);
    GLOAD16(A + (long long)(m0 + (c1 >> 2)) * K + kt + (c1 & 3) * 8,
            (char*)As + (w * 64 + 256) * 16);
    GLOAD16(Bt + (long long)(n0 + (c0 >> 2)) * K + kt + (c0 & 3) * 8,
            (char*)Bs + (w * 64) * 16);
    GLOAD16(Bt + (long long)(n0 + (c1 >> 2)) * K + kt + (c1 & 3) * 8,
            (char*)Bs + (w * 64 + 256) * 16);
    __syncthreads();

    bf16x8 af[4], bfr[4];
#pragma unroll
    for (int mi = 0; mi < 4; mi++)
      af[mi] = *(const bf16x8*)(As + (wr * 64 + mi * 16 + l15) * 32 + lg * 8);
#pragma unroll
    for (int ni = 0; ni < 4; ni++)
      bfr[ni] = *(const bf16x8*)(Bs + (wc * 64 + ni * 16 + l15) * 32 + lg * 8);
#pragma unroll
    for (int mi = 0; mi < 4; mi++)
#pragma unroll
      for (int ni = 0; ni < 4; ni++)
        acc[mi][ni] = mfma_bf16(af[mi], bfr[ni], acc[mi][ni]);
  }

  const int row0 = m0 + wr * 64, col0 = n0 + wc * 64;
#pragma unroll
  for (int mi = 0; mi < 4; mi++)
#pragma unroll
    for (int ni = 0; ni < 4; ni++) {
      int rbase = row0 + mi * 16 + lg * 4;
      int col = col0 + ni * 16 + l15;
#pragma unroll
      for (int r = 0; r < 4; r++) {
        float v = acc[mi][ni][r];
        if (EPI == 0)
          ((unsigned short*)Cv)[(long long)(rbase + r) * N + col] = f2bf(v);
        else if (EPI == 1)
          ((unsigned short*)Cv)[(long long)col * M + (rbase + r)] = f2bf(v);
        else
          ((float*)Cv)[(long long)(rbase + r) * N + col] = v;
      }
    }
}

// ---------------------------------------------------------------- RoPE (neox, fp64 angles) on bf16 [T][H*128]
__global__ void rope_bf(unsigned short* __restrict__ buf,
                        const int* __restrict__ positions, int H) {
  const int w = threadIdx.x >> 6, d = threadIdx.x & 63;
  const int gid = blockIdx.x * 4 + w;  // t*H + h
  const int h = gid % H, t = gid / H;
  double inv = exp2(-(double)d * 0.20762050593046014);  // 10000^(-d/64)
  double ang = (double)positions[t] * inv;
  double c = cos(ang), s = sin(ang);
  unsigned short* row = buf + (size_t)t * (H * HDIM) + (size_t)h * HDIM;
  float x1 = bf2f(row[d]), x2 = bf2f(row[d + 64]);
  row[d]      = f2bf((float)((double)x1 * c - (double)x2 * s));
  row[d + 64] = f2bf((float)((double)x2 * c + (double)x1 * s));
}

// ---------------------------------------------------------------- flash attention v2
// grid: (T/64, NQH); block 256 = 4 waves x 16 q-rows; KBLK=64; Q in registers;
// XOR-swizzled K/V/P LDS (linear gload_lds dest + pre-swizzled global source).
__global__ __launch_bounds__(256) void attn_kernel(const unsigned short* __restrict__ qb,
                                                   const unsigned short* __restrict__ kb,
                                                   const unsigned short* __restrict__ vt,
                                                   unsigned short* __restrict__ ab) {
  __shared__ unsigned short Ks[64 * 128];
  __shared__ unsigned short Vs[128 * 64];
  __shared__ unsigned short Ps[4][16 * 64];

  const int qblk = gridDim.x - 1 - blockIdx.x;  // long blocks first
  const int h = blockIdx.y;
  const int kvh = h >> 2;
  const int q0 = qblk * 64;
  const int t = threadIdx.x, lane = t & 63, w = t >> 6;
  const int l15 = lane & 15, lg = lane >> 4;

  // Q fragments in registers: row q0 + w*16 + l15, k = kk*32 + lg*8
  bf16x8 qf[4];
#pragma unroll
  for (int kk = 0; kk < 4; kk++)
    qf[kk] = *(const bf16x8*)(qb + (long long)(q0 + w * 16 + l15) * (NQH * HDIM) +
                              h * HDIM + kk * 32 + lg * 8);

  f32x4 accO[8];
#pragma unroll
  for (int db = 0; db < 8; db++) accO[db] = (f32x4){0.f, 0.f, 0.f, 0.f};
  float mrun[4] = {-3e38f, -3e38f, -3e38f, -3e38f};
  float lrun[4] = {0.f, 0.f, 0.f, 0.f};

  const int nkt = qblk + 1;
  for (int kt = 0; kt < nkt; kt++) {
    __syncthreads();
    // K tile (64 x 128 bf16): 1024 chunks, swizzled source (chunk ^= row&7)
#pragma unroll
    for (int s = 0; s < 4; s++) {
      int c = t + s * 256;
      int row = c >> 4, chk = c & 15;
      GLOAD16(kb + (long long)(kt * 64 + row) * (NKVH * HDIM) + kvh * HDIM +
                  ((chk ^ (row & 7)) * 8),
              (char*)Ks + (w * 64 + s * 256) * 16);
    }
    // Vt tile (128 x 64): 1024 chunks, swizzled source
#pragma unroll
    for (int s = 0; s < 4; s++) {
      int c = t + s * 256;
      int row = c >> 3, chk = c & 7;
      GLOAD16(vt + (long long)(kvh * HDIM + row) * T_SEQ + kt * 64 +
                  ((chk ^ (row & 7)) * 8),
              (char*)Vs + (w * 64 + s * 256) * 16);
    }
    __syncthreads();

    // S = Q K^T : wave's 16 q-rows x 64 k-cols
    f32x4 accS[4];
#pragma unroll
    for (int kc = 0; kc < 4; kc++) accS[kc] = (f32x4){0.f, 0.f, 0.f, 0.f};
#pragma unroll
    for (int kk = 0; kk < 4; kk++)
#pragma unroll
      for (int kc = 0; kc < 4; kc++) {
        int row = kc * 16 + l15;
        bf16x8 b = *(const bf16x8*)(Ks + row * 128 + (((kk * 4 + lg) ^ (l15 & 7)) * 8));
        accS[kc] = mfma_bf16(qf[kk], b, accS[kc]);
      }

    // scale + causal mask
    const float sc = 0.08838834764831845f;
    const int qrow = q0 + w * 16 + lg * 4;  // + r
    float pm[4][4];
#pragma unroll
    for (int kc = 0; kc < 4; kc++) {
      int kcol = kt * 64 + kc * 16 + l15;
#pragma unroll
      for (int r = 0; r < 4; r++) {
        float sv = accS[kc][r] * sc;
        pm[kc][r] = (kcol > qrow + r) ? -3e38f : sv;
      }
    }
    // row max over 64 cols (16 lanes x 4 regs)
    float rm[4];
#pragma unroll
    for (int r = 0; r < 4; r++)
      rm[r] = fmaxf(fmaxf(pm[0][r], pm[1][r]), fmaxf(pm[2][r], pm[3][r]));
#pragma unroll
    for (int off = 1; off < 16; off <<= 1)
#pragma unroll
      for (int r = 0; r < 4; r++) rm[r] = fmaxf(rm[r], __shfl_xor(rm[r], off, 64));
    float corr[4];
#pragma unroll
    for (int r = 0; r < 4; r++) {
      float mn = fmaxf(mrun[r], rm[r]);
      corr[r] = __expf(mrun[r] - mn);
      mrun[r] = mn;
    }
    float rs[4] = {0.f, 0.f, 0.f, 0.f};
    unsigned short pb[4][4];
#pragma unroll
    for (int kc = 0; kc < 4; kc++)
#pragma unroll
      for (int r = 0; r < 4; r++) {
        float p = __expf(pm[kc][r] - mrun[r]);
        rs[r] += p;
        pb[kc][r] = f2bf(p);
      }
#pragma unroll
    for (int off = 1; off < 16; off <<= 1)
#pragma unroll
      for (int r = 0; r < 4; r++) rs[r] += __shfl_xor(rs[r], off, 64);
#pragma unroll
    for (int r = 0; r < 4; r++) lrun[r] = lrun[r] * corr[r] + rs[r];
#pragma unroll
    for (int db = 0; db < 8; db++)
#pragma unroll
      for (int r = 0; r < 4; r++) accO[db][r] *= corr[r];

    // P -> LDS (wave-private, swizzled elem ^= (row&7)<<3)
    unsigned short* Pw = Ps[w];
#pragma unroll
    for (int kc = 0; kc < 4; kc++)
#pragma unroll
      for (int r = 0; r < 4; r++) {
        int prow = lg * 4 + r;
        Pw[(prow * 64 + kc * 16 + l15) ^ ((prow & 7) << 3)] = pb[kc][r];
      }
    asm volatile("s_waitcnt lgkmcnt(0)" ::: "memory");

    // O += P * V  (two K=32 slices over 64 k-cols)
#pragma unroll
    for (int ks = 0; ks < 2; ks++) {
      bf16x8 pa = *(const bf16x8*)(Pw + ((l15 * 64 + ks * 32 + lg * 8) ^ ((l15 & 7) << 3)));
#pragma unroll
      for (int db = 0; db < 8; db++) {
        int row = db * 16 + l15;
        bf16x8 b = *(const bf16x8*)(Vs + row * 64 + ((ks * 32 + lg * 8) ^ ((l15 & 7) << 3)));
        accO[db] = mfma_bf16(pa, b, accO[db]);
      }
    }
  }

  // epilogue: O / l -> ab bf16 [T][NQH*HDIM]
#pragma unroll
  for (int db = 0; db < 8; db++)
#pragma unroll
    for (int r = 0; r < 4; r++) {
      int qr = q0 + w * 16 + lg * 4 + r;
      int col = h * HDIM + db * 16 + l15;
      ab[(long long)qr * (NQH * HDIM) + col] = f2bf(accO[db][r] / lrun[r]);
    }
}

// ---------------------------------------------------------------- launch
extern "C" void kernel_launch(void* const* d_in, const int* in_sizes, int n_in,
                              void* d_out, int out_size, void* d_ws, size_t ws_size,
                              hipStream_t stream) {
  const int*   positions = (const int*)d_in[0];
  const float* hs = (const float*)d_in[1];
  const float* wq = (const float*)d_in[2];
  const float* wk = (const float*)d_in[3];
  const float* wv = (const float*)d_in[4];
  const float* wo = (const float*)d_in[5];
  float* out = (float*)d_out;

  // workspace: wt 33.6 + hb/ab 16.8 + qb 16.8 + kb 4.2 + vt 4.2 = 75.5 MB
  const size_t SZ_WT = (size_t)HID * HID * 2;              // 33.6 MB (max weight)
  const size_t SZ_HB = (size_t)T_SEQ * HID * 2;            // 16.8 MB
  const size_t SZ_QB = (size_t)T_SEQ * NQH * HDIM * 2;     // 16.8 MB
  const size_t SZ_KB = (size_t)T_SEQ * NKVH * HDIM * 2;    //  4.2 MB
  const size_t need = SZ_WT + SZ_HB + SZ_QB + SZ_KB * 2;
  if (ws_size < need) return;  // absmax 4.625 signature

  char* p = (char*)d_ws;
  unsigned short* wt  = (unsigned short*)p; p += SZ_WT;  // reused for wq/wk/wv/wo
  unsigned short* hb  = (unsigned short*)p; p += SZ_HB;  // hidden bf16; later ab
  unsigned short* qb  = (unsigned short*)p; p += SZ_QB;
  unsigned short* kb  = (unsigned short*)p; p += SZ_KB;
  unsigned short* vtb = (unsigned short*)p; p += SZ_KB;
  unsigned short* ab  = hb;                              // alias: hb dead after V-GEMM

  conv_f32_bf16<<<(T_SEQ * HID) / 1024, 256, 0, stream>>>(hs, hb);

  transpose_conv<<<dim3((NQH * HDIM) / 32, HID / 32), 256, 0, stream>>>(wq, wt, HID, NQH * HDIM);
  gemm_bt<0><<<dim3((NQH * HDIM) / 128, T_SEQ / 128), 256, 0, stream>>>(hb, wt, qb, T_SEQ, NQH * HDIM, HID);

  transpose_conv<<<dim3((NKVH * HDIM) / 32, HID / 32), 256, 0, stream>>>(wk, wt, HID, NKVH * HDIM);
  gemm_bt<0><<<dim3((NKVH * HDIM) / 128, T_SEQ / 128), 256, 0, stream>>>(hb, wt, kb, T_SEQ, NKVH * HDIM, HID);

  transpose_conv<<<dim3((NKVH * HDIM) / 32, HID / 32), 256, 0, stream>>>(wv, wt, HID, NKVH * HDIM);
  gemm_bt<1><<<dim3((NKVH * HDIM) / 128, T_SEQ / 128), 256, 0, stream>>>(hb, wt, vtb, T_SEQ, NKVH * HDIM, HID);

  rope_bf<<<(T_SEQ * NQH) / 4, 256, 0, stream>>>(qb, positions, NQH);
  rope_bf<<<(T_SEQ * NKVH) / 4, 256, 0, stream>>>(kb, positions, NKVH);

  attn_kernel<<<dim3(T_SEQ / 64, NQH), 256, 0, stream>>>(qb, kb, vtb, ab);

  transpose_conv<<<dim3(HID / 32, (NQH * HDIM) / 32), 256, 0, stream>>>(wo, wt, NQH * HDIM, HID);
  gemm_bt<2><<<dim3(HID / 128, T_SEQ / 128), 256, 0, stream>>>(ab, wt, out, T_SEQ, HID, NQH * HDIM);
}

// Round 7
// 537.726 us; speedup vs baseline: 13.0284x; 1.1836x over previous
//
#include <hip/hip_runtime.h>

#define T_SEQ  2048
#define HID    4096
#define NQH    32
#define NKVH   8
#define HDIM   128

typedef float  f32x4  __attribute__((ext_vector_type(4)));
typedef __bf16 bf16x8 __attribute__((ext_vector_type(8)));

__device__ __forceinline__ float bf2f(unsigned short u) {
  union { unsigned int i; float f; } v; v.i = ((unsigned int)u) << 16; return v.f;
}
__device__ __forceinline__ unsigned short f2bf(float f) {
  union { float f; unsigned int i; } v; v.f = f;
  unsigned int r = v.i + 0x7fffu + ((v.i >> 16) & 1u);
  return (unsigned short)(r >> 16);
}

__device__ __forceinline__ f32x4 mfma_bf16(bf16x8 a, bf16x8 b, f32x4 c) {
  return __builtin_amdgcn_mfma_f32_16x16x32_bf16(a, b, c, 0, 0, 0);
}

#define GLOAD16(g, l)                                              \
  __builtin_amdgcn_global_load_lds(                                \
      (const __attribute__((address_space(1))) void*)(g),          \
      (__attribute__((address_space(3))) void*)(l), 16, 0, 0)

// ---------------------------------------------------------------- convert
__global__ void conv_f32_bf16(const float* __restrict__ in,
                              unsigned short* __restrict__ out) {
  long long i = ((long long)blockIdx.x * 256 + threadIdx.x) * 4;
  float4 v = *(const float4*)(in + i);
  union { unsigned short u[4]; uint2 p; } o;
  o.u[0] = f2bf(v.x); o.u[1] = f2bf(v.y); o.u[2] = f2bf(v.z); o.u[3] = f2bf(v.w);
  *(uint2*)(out + i) = o.p;
}

// W[K][N] fp32  ->  Wt[N][K] bf16
__global__ void transpose_conv(const float* __restrict__ W,
                               unsigned short* __restrict__ Wt, int K, int N) {
  __shared__ float tile[32][33];
  int n0 = blockIdx.x * 32, k0 = blockIdx.y * 32;
  int tx = threadIdx.x & 31, ty = threadIdx.x >> 5;  // ty 0..7
#pragma unroll
  for (int r = 0; r < 32; r += 8)
    tile[ty + r][tx] = W[(long long)(k0 + ty + r) * N + n0 + tx];
  __syncthreads();
#pragma unroll
  for (int r = 0; r < 32; r += 8)
    Wt[(long long)(n0 + ty + r) * K + k0 + tx] = f2bf(tile[tx][ty + r]);
}

// ---------------------------------------------------------------- GEMM (m97 structure)
// C[M,N] = A[M,K](bf16,row-major) * Bt[N,K](bf16,row-major)^T
// EPI: 0 = bf16 row-major out; 2 = fp32 row-major out;
//      3 = KV split: cols<1024 -> Cv (bf16 [M][1024]), cols>=1024 -> Cv2 transposed [1024][M]
template <int EPI>
__global__ __launch_bounds__(256) void gemm_bt(const unsigned short* __restrict__ A,
                                               const unsigned short* __restrict__ Bt,
                                               void* __restrict__ Cv,
                                               void* __restrict__ Cv2,
                                               int M, int N, int K) {
  __shared__ unsigned short As[128 * 32];
  __shared__ unsigned short Bs[128 * 32];
  const int t = threadIdx.x;
  const int lane = t & 63, w = t >> 6;
  const int wr = w >> 1, wc = w & 1;
  const int l15 = lane & 15, lg = lane >> 4;
  const int m0 = blockIdx.y * 128, n0 = blockIdx.x * 128;

  f32x4 acc[4][4];
#pragma unroll
  for (int i = 0; i < 4; i++)
#pragma unroll
    for (int j = 0; j < 4; j++) acc[i][j] = (f32x4){0.f, 0.f, 0.f, 0.f};

  const int c0 = t, c1 = t + 256;  // 16B chunks (row = c>>2, sub = c&3)

  for (int kt = 0; kt < K; kt += 32) {
    __syncthreads();
    GLOAD16(A + (long long)(m0 + (c0 >> 2)) * K + kt + (c0 & 3) * 8,
            (char*)As + (w * 64) * 16);
    GLOAD16(A + (long long)(m0 + (c1 >> 2)) * K + kt + (c1 & 3) * 8,
            (char*)As + (w * 64 + 256) * 16);
    GLOAD16(Bt + (long long)(n0 + (c0 >> 2)) * K + kt + (c0 & 3) * 8,
            (char*)Bs + (w * 64) * 16);
    GLOAD16(Bt + (long long)(n0 + (c1 >> 2)) * K + kt + (c1 & 3) * 8,
            (char*)Bs + (w * 64 + 256) * 16);
    __syncthreads();

    bf16x8 af[4], bfr[4];
#pragma unroll
    for (int mi = 0; mi < 4; mi++)
      af[mi] = *(const bf16x8*)(As + (wr * 64 + mi * 16 + l15) * 32 + lg * 8);
#pragma unroll
    for (int ni = 0; ni < 4; ni++)
      bfr[ni] = *(const bf16x8*)(Bs + (wc * 64 + ni * 16 + l15) * 32 + lg * 8);
#pragma unroll
    for (int mi = 0; mi < 4; mi++)
#pragma unroll
      for (int ni = 0; ni < 4; ni++)
        acc[mi][ni] = mfma_bf16(af[mi], bfr[ni], acc[mi][ni]);
  }

  const int row0 = m0 + wr * 64, col0 = n0 + wc * 64;
#pragma unroll
  for (int mi = 0; mi < 4; mi++)
#pragma unroll
    for (int ni = 0; ni < 4; ni++) {
      int rbase = row0 + mi * 16 + lg * 4;
      int col = col0 + ni * 16 + l15;
#pragma unroll
      for (int r = 0; r < 4; r++) {
        float v = acc[mi][ni][r];
        if (EPI == 0)
          ((unsigned short*)Cv)[(long long)(rbase + r) * N + col] = f2bf(v);
        else if (EPI == 2)
          ((float*)Cv)[(long long)(rbase + r) * N + col] = v;
        else {  // EPI == 3
          if (col < 1024)
            ((unsigned short*)Cv)[(long long)(rbase + r) * 1024 + col] = f2bf(v);
          else
            ((unsigned short*)Cv2)[(long long)(col - 1024) * T_SEQ + (rbase + r)] = f2bf(v);
        }
      }
    }
}

// ---------------------------------------------------------------- RoPE (neox, fp64 angles) on bf16 [T][H*128]
__global__ void rope_bf(unsigned short* __restrict__ buf,
                        const int* __restrict__ positions, int H) {
  const int w = threadIdx.x >> 6, d = threadIdx.x & 63;
  const int gid = blockIdx.x * 4 + w;  // t*H + h
  const int h = gid % H, t = gid / H;
  double inv = exp2(-(double)d * 0.20762050593046014);  // 10000^(-d/64)
  double ang = (double)positions[t] * inv;
  double c = cos(ang), s = sin(ang);
  unsigned short* row = buf + (size_t)t * (H * HDIM) + (size_t)h * HDIM;
  float x1 = bf2f(row[d]), x2 = bf2f(row[d + 64]);
  row[d]      = f2bf((float)((double)x1 * c - (double)x2 * s));
  row[d + 64] = f2bf((float)((double)x2 * c + (double)x1 * s));
}

// ---------------------------------------------------------------- flash attention v3
// One body = 16 q-rows x 64 k-cols for one wave. exp2-domain softmax, defer-max.
__device__ __forceinline__ void attn_body(const unsigned short* __restrict__ Ksb,
                                          const unsigned short* __restrict__ Vsb,
                                          unsigned short* __restrict__ Pw,
                                          const bf16x8 qf[4], f32x4 accO[8],
                                          float mrun[4], float lrun[4],
                                          int qrow0, int kt, int l15, int lg) {
  // S = Q K^T
  f32x4 accS[4];
#pragma unroll
  for (int kc = 0; kc < 4; kc++) accS[kc] = (f32x4){0.f, 0.f, 0.f, 0.f};
#pragma unroll
  for (int kk = 0; kk < 4; kk++)
#pragma unroll
    for (int kc = 0; kc < 4; kc++) {
      int row = kc * 16 + l15;
      bf16x8 b = *(const bf16x8*)(Ksb + row * 128 + (((kk * 4 + lg) ^ (l15 & 7)) * 8));
      accS[kc] = mfma_bf16(qf[kk], b, accS[kc]);
    }

  // scale into log2 domain + causal mask
  const float sc2 = 0.1275174441698669f;  // 1/sqrt(128) * log2(e)
  float pm[4][4];
#pragma unroll
  for (int kc = 0; kc < 4; kc++) {
    int kcol = kt * 64 + kc * 16 + l15;
#pragma unroll
    for (int r = 0; r < 4; r++) {
      float sv = accS[kc][r] * sc2;
      pm[kc][r] = (kcol > qrow0 + lg * 4 + r) ? -3e38f : sv;
    }
  }
  // row max over 64 cols
  float rm[4];
#pragma unroll
  for (int r = 0; r < 4; r++)
    rm[r] = fmaxf(fmaxf(pm[0][r], pm[1][r]), fmaxf(pm[2][r], pm[3][r]));
#pragma unroll
  for (int off = 1; off < 16; off <<= 1)
#pragma unroll
    for (int r = 0; r < 4; r++) rm[r] = fmaxf(rm[r], __shfl_xor(rm[r], off, 64));

  // defer-max (THR = 8 in log2 domain -> P bounded by 256)
  bool need = false;
#pragma unroll
  for (int r = 0; r < 4; r++) need = need || (rm[r] > mrun[r] + 8.f);
  if (need) {
#pragma unroll
    for (int r = 0; r < 4; r++) {
      float mn = fmaxf(mrun[r], rm[r]);
      float corr = exp2f(mrun[r] - mn);
      mrun[r] = mn;
      lrun[r] *= corr;
#pragma unroll
      for (int db = 0; db < 8; db++) accO[db][r] *= corr;
    }
  }

  float rs[4] = {0.f, 0.f, 0.f, 0.f};
  __bf16 pbh[4][4];
#pragma unroll
  for (int kc = 0; kc < 4; kc++)
#pragma unroll
    for (int r = 0; r < 4; r++) {
      float p = exp2f(pm[kc][r] - mrun[r]);
      rs[r] += p;
      pbh[kc][r] = (__bf16)p;
    }
#pragma unroll
  for (int off = 1; off < 16; off <<= 1)
#pragma unroll
    for (int r = 0; r < 4; r++) rs[r] += __shfl_xor(rs[r], off, 64);
#pragma unroll
  for (int r = 0; r < 4; r++) lrun[r] += rs[r];

  // P -> LDS (wave-private, swizzled)
#pragma unroll
  for (int kc = 0; kc < 4; kc++)
#pragma unroll
    for (int r = 0; r < 4; r++) {
      int prow = lg * 4 + r;
      ((__bf16*)Pw)[(prow * 64 + kc * 16 + l15) ^ ((prow & 7) << 3)] = pbh[kc][r];
    }
  asm volatile("s_waitcnt lgkmcnt(0)" ::: "memory");

  // O += P * V
#pragma unroll
  for (int ks = 0; ks < 2; ks++) {
    bf16x8 pa = *(const bf16x8*)(Pw + ((l15 * 64 + ks * 32 + lg * 8) ^ ((l15 & 7) << 3)));
#pragma unroll
    for (int db = 0; db < 8; db++) {
      int row = db * 16 + l15;
      bf16x8 b = *(const bf16x8*)(Vsb + row * 64 + ((ks * 32 + lg * 8) ^ ((l15 & 7) << 3)));
      accO[db] = mfma_bf16(pa, b, accO[db]);
    }
  }
}

// grid: (16, NQH); block 256 = 4 waves x 16 q-rows.
// Block bx processes q-tiles jA = 31-bx (long) and jB = bx (short): uniform 33 bodies.
// K/V double-buffered LDS with next-tile prefetch (2-phase pipeline).
__global__ __launch_bounds__(256) void attn_kernel(const unsigned short* __restrict__ qb,
                                                   const unsigned short* __restrict__ kb,
                                                   const unsigned short* __restrict__ vt,
                                                   unsigned short* __restrict__ ab) {
  __shared__ unsigned short Ks[2][64 * 128];
  __shared__ unsigned short Vs[2][128 * 64];
  __shared__ unsigned short Ps[4][2][16 * 64];

  const int bx = blockIdx.x;
  const int h = blockIdx.y;
  const int kvh = h >> 2;
  const int jA = 31 - bx, jB = bx;
  const int q0A = jA * 64, q0B = jB * 64;
  const int t = threadIdx.x, lane = t & 63, w = t >> 6;
  const int l15 = lane & 15, lg = lane >> 4;

  // Q fragments in registers
  bf16x8 qfA[4], qfB[4];
#pragma unroll
  for (int kk = 0; kk < 4; kk++) {
    qfA[kk] = *(const bf16x8*)(qb + (long long)(q0A + w * 16 + l15) * (NQH * HDIM) +
                               h * HDIM + kk * 32 + lg * 8);
    qfB[kk] = *(const bf16x8*)(qb + (long long)(q0B + w * 16 + l15) * (NQH * HDIM) +
                               h * HDIM + kk * 32 + lg * 8);
  }

  f32x4 accA[8], accB[8];
#pragma unroll
  for (int db = 0; db < 8; db++) {
    accA[db] = (f32x4){0.f, 0.f, 0.f, 0.f};
    accB[db] = (f32x4){0.f, 0.f, 0.f, 0.f};
  }
  float mA[4] = {-3e38f, -3e38f, -3e38f, -3e38f}, lA[4] = {0.f, 0.f, 0.f, 0.f};
  float mB[4] = {-3e38f, -3e38f, -3e38f, -3e38f}, lB[4] = {0.f, 0.f, 0.f, 0.f};

  auto stage = [&](int kts, int b) {
#pragma unroll
    for (int s = 0; s < 4; s++) {
      int c = t + s * 256;
      int row = c >> 4, chk = c & 15;
      GLOAD16(kb + (long long)(kts * 64 + row) * (NKVH * HDIM) + kvh * HDIM +
                  ((chk ^ (row & 7)) * 8),
              (char*)(&Ks[b][0]) + (w * 64 + s * 256) * 16);
    }
#pragma unroll
    for (int s = 0; s < 4; s++) {
      int c = t + s * 256;
      int row = c >> 3, chk = c & 7;
      GLOAD16(vt + (long long)(kvh * HDIM + row) * T_SEQ + kts * 64 +
                  ((chk ^ (row & 7)) * 8),
              (char*)(&Vs[b][0]) + (w * 64 + s * 256) * 16);
    }
  };

  const int nt = jA + 1;
  stage(0, 0);
  for (int kt = 0; kt < nt; kt++) {
    const int cur = kt & 1;
    __syncthreads();
    if (kt + 1 < nt) stage(kt + 1, cur ^ 1);
    attn_body(&Ks[cur][0], &Vs[cur][0], &Ps[w][0][0],
              qfA, accA, mA, lA, q0A + w * 16, kt, l15, lg);
    if (kt <= jB)
      attn_body(&Ks[cur][0], &Vs[cur][0], &Ps[w][1][0],
                qfB, accB, mB, lB, q0B + w * 16, kt, l15, lg);
  }

  // epilogue
#pragma unroll
  for (int db = 0; db < 8; db++)
#pragma unroll
    for (int r = 0; r < 4; r++) {
      int col = h * HDIM + db * 16 + l15;
      int qrA = q0A + w * 16 + lg * 4 + r;
      int qrB = q0B + w * 16 + lg * 4 + r;
      ((__bf16*)ab)[(long long)qrA * (NQH * HDIM) + col] = (__bf16)(accA[db][r] / lA[r]);
      ((__bf16*)ab)[(long long)qrB * (NQH * HDIM) + col] = (__bf16)(accB[db][r] / lB[r]);
    }
}

// ---------------------------------------------------------------- launch
extern "C" void kernel_launch(void* const* d_in, const int* in_sizes, int n_in,
                              void* d_out, int out_size, void* d_ws, size_t ws_size,
                              hipStream_t stream) {
  const int*   positions = (const int*)d_in[0];
  const float* hs = (const float*)d_in[1];
  const float* wq = (const float*)d_in[2];
  const float* wk = (const float*)d_in[3];
  const float* wv = (const float*)d_in[4];
  const float* wo = (const float*)d_in[5];
  float* out = (float*)d_out;

  // workspace: wt 33.6 + hb/ab 16.8 + qb 16.8 + kb 4.2 + vt 4.2 = 75.5 MB
  const size_t SZ_WT = (size_t)HID * HID * 2;
  const size_t SZ_HB = (size_t)T_SEQ * HID * 2;
  const size_t SZ_QB = (size_t)T_SEQ * NQH * HDIM * 2;
  const size_t SZ_KB = (size_t)T_SEQ * NKVH * HDIM * 2;
  const size_t need = SZ_WT + SZ_HB + SZ_QB + SZ_KB * 2;
  if (ws_size < need) return;  // absmax 4.625 signature

  char* p = (char*)d_ws;
  unsigned short* wt  = (unsigned short*)p; p += SZ_WT;  // wq_t, then wk_t+wv_t, then wo_t
  unsigned short* hb  = (unsigned short*)p; p += SZ_HB;  // hidden bf16; later ab
  unsigned short* qb  = (unsigned short*)p; p += SZ_QB;
  unsigned short* kb  = (unsigned short*)p; p += SZ_KB;
  unsigned short* vtb = (unsigned short*)p; p += SZ_KB;
  unsigned short* ab  = hb;                              // alias: hb dead after KV-GEMM

  conv_f32_bf16<<<(T_SEQ * HID) / 1024, 256, 0, stream>>>(hs, hb);

  // Q projection
  transpose_conv<<<dim3((NQH * HDIM) / 32, HID / 32), 256, 0, stream>>>(wq, wt, HID, NQH * HDIM);
  gemm_bt<0><<<dim3((NQH * HDIM) / 128, T_SEQ / 128), 256, 0, stream>>>(hb, wt, qb, nullptr, T_SEQ, NQH * HDIM, HID);

  // K + V projection fused (N = 2048)
  transpose_conv<<<dim3((NKVH * HDIM) / 32, HID / 32), 256, 0, stream>>>(wk, wt, HID, NKVH * HDIM);
  transpose_conv<<<dim3((NKVH * HDIM) / 32, HID / 32), 256, 0, stream>>>(wv, wt + (size_t)(NKVH * HDIM) * HID, HID, NKVH * HDIM);
  gemm_bt<3><<<dim3((2 * NKVH * HDIM) / 128, T_SEQ / 128), 256, 0, stream>>>(hb, wt, kb, vtb, T_SEQ, 2 * NKVH * HDIM, HID);

  rope_bf<<<(T_SEQ * NQH) / 4, 256, 0, stream>>>(qb, positions, NQH);
  rope_bf<<<(T_SEQ * NKVH) / 4, 256, 0, stream>>>(kb, positions, NKVH);

  attn_kernel<<<dim3(16, NQH), 256, 0, stream>>>(qb, kb, vtb, ab);

  // output projection
  transpose_conv<<<dim3(HID / 32, (NQH * HDIM) / 32), 256, 0, stream>>>(wo, wt, NQH * HDIM, HID);
  gemm_bt<2><<<dim3(HID / 128, T_SEQ / 128), 256, 0, stream>>>(ab, wt, out, nullptr, T_SEQ, HID, NQH * HDIM);
}

// Round 8
// 507.407 us; speedup vs baseline: 13.8069x; 1.0598x over previous
//
#include <hip/hip_runtime.h>

#define T_SEQ  2048
#define HID    4096
#define NQH    32
#define NKVH   8
#define HDIM   128

typedef float  f32x4  __attribute__((ext_vector_type(4)));
typedef __bf16 bf16x8 __attribute__((ext_vector_type(8)));

__device__ __forceinline__ float bf2f(unsigned short u) {
  union { unsigned int i; float f; } v; v.i = ((unsigned int)u) << 16; return v.f;
}
__device__ __forceinline__ unsigned short f2bf(float f) {
  union { float f; unsigned int i; } v; v.f = f;
  unsigned int r = v.i + 0x7fffu + ((v.i >> 16) & 1u);
  return (unsigned short)(r >> 16);
}

__device__ __forceinline__ f32x4 mfma_bf16(bf16x8 a, bf16x8 b, f32x4 c) {
  return __builtin_amdgcn_mfma_f32_16x16x32_bf16(a, b, c, 0, 0, 0);
}

#define GLOAD16(g, l)                                              \
  __builtin_amdgcn_global_load_lds(                                \
      (const __attribute__((address_space(1))) void*)(g),          \
      (__attribute__((address_space(3))) void*)(l), 16, 0, 0)

// ---------------------------------------------------------------- convert
__global__ void conv_f32_bf16(const float* __restrict__ in,
                              unsigned short* __restrict__ out) {
  long long i = ((long long)blockIdx.x * 256 + threadIdx.x) * 4;
  float4 v = *(const float4*)(in + i);
  union { unsigned short u[4]; uint2 p; } o;
  o.u[0] = f2bf(v.x); o.u[1] = f2bf(v.y); o.u[2] = f2bf(v.z); o.u[3] = f2bf(v.w);
  *(uint2*)(out + i) = o.p;
}

// W[K][N] fp32  ->  Wt[N][K] bf16
__global__ void transpose_conv(const float* __restrict__ W,
                               unsigned short* __restrict__ Wt, int K, int N) {
  __shared__ float tile[32][33];
  int n0 = blockIdx.x * 32, k0 = blockIdx.y * 32;
  int tx = threadIdx.x & 31, ty = threadIdx.x >> 5;  // ty 0..7
#pragma unroll
  for (int r = 0; r < 32; r += 8)
    tile[ty + r][tx] = W[(long long)(k0 + ty + r) * N + n0 + tx];
  __syncthreads();
#pragma unroll
  for (int r = 0; r < 32; r += 8)
    Wt[(long long)(n0 + ty + r) * K + k0 + tx] = f2bf(tile[tx][ty + r]);
}

// ---------------------------------------------------------------- GEMM (m97 structure + XCD swizzle)
// C[M,N] = A[M,K](bf16,row-major) * Bt[N,K](bf16,row-major)^T
// EPI: 0 = bf16 row-major out; 2 = fp32 row-major out;
//      3 = KV split: cols<1024 -> Cv (bf16 [M][1024]), cols>=1024 -> Cv2 transposed [1024][M]
template <int EPI>
__global__ __launch_bounds__(256) void gemm_bt(const unsigned short* __restrict__ A,
                                               const unsigned short* __restrict__ Bt,
                                               void* __restrict__ Cv,
                                               void* __restrict__ Cv2,
                                               int M, int N, int K) {
  __shared__ unsigned short As[128 * 32];
  __shared__ unsigned short Bs[128 * 32];
  // XCD-aware bijective swizzle (grid sizes here are all multiples of 8)
  const int lin = blockIdx.y * gridDim.x + blockIdx.x;
  const int cpx = (gridDim.x * gridDim.y) >> 3;
  const int swz = (lin & 7) * cpx + (lin >> 3);
  const int bx = swz % gridDim.x, by = swz / gridDim.x;

  const int t = threadIdx.x;
  const int lane = t & 63, w = t >> 6;
  const int wr = w >> 1, wc = w & 1;
  const int l15 = lane & 15, lg = lane >> 4;
  const int m0 = by * 128, n0 = bx * 128;

  f32x4 acc[4][4];
#pragma unroll
  for (int i = 0; i < 4; i++)
#pragma unroll
    for (int j = 0; j < 4; j++) acc[i][j] = (f32x4){0.f, 0.f, 0.f, 0.f};

  const int c0 = t, c1 = t + 256;  // 16B chunks (row = c>>2, sub = c&3)

  for (int kt = 0; kt < K; kt += 32) {
    __syncthreads();
    GLOAD16(A + (long long)(m0 + (c0 >> 2)) * K + kt + (c0 & 3) * 8,
            (char*)As + (w * 64) * 16);
    GLOAD16(A + (long long)(m0 + (c1 >> 2)) * K + kt + (c1 & 3) * 8,
            (char*)As + (w * 64 + 256) * 16);
    GLOAD16(Bt + (long long)(n0 + (c0 >> 2)) * K + kt + (c0 & 3) * 8,
            (char*)Bs + (w * 64) * 16);
    GLOAD16(Bt + (long long)(n0 + (c1 >> 2)) * K + kt + (c1 & 3) * 8,
            (char*)Bs + (w * 64 + 256) * 16);
    __syncthreads();

    bf16x8 af[4], bfr[4];
#pragma unroll
    for (int mi = 0; mi < 4; mi++)
      af[mi] = *(const bf16x8*)(As + (wr * 64 + mi * 16 + l15) * 32 + lg * 8);
#pragma unroll
    for (int ni = 0; ni < 4; ni++)
      bfr[ni] = *(const bf16x8*)(Bs + (wc * 64 + ni * 16 + l15) * 32 + lg * 8);
#pragma unroll
    for (int mi = 0; mi < 4; mi++)
#pragma unroll
      for (int ni = 0; ni < 4; ni++)
        acc[mi][ni] = mfma_bf16(af[mi], bfr[ni], acc[mi][ni]);
  }

  const int row0 = m0 + wr * 64, col0 = n0 + wc * 64;
#pragma unroll
  for (int mi = 0; mi < 4; mi++)
#pragma unroll
    for (int ni = 0; ni < 4; ni++) {
      int rbase = row0 + mi * 16 + lg * 4;
      int col = col0 + ni * 16 + l15;
#pragma unroll
      for (int r = 0; r < 4; r++) {
        float v = acc[mi][ni][r];
        if (EPI == 0)
          ((unsigned short*)Cv)[(long long)(rbase + r) * N + col] = f2bf(v);
        else if (EPI == 2)
          ((float*)Cv)[(long long)(rbase + r) * N + col] = v;
        else {  // EPI == 3
          if (col < 1024)
            ((unsigned short*)Cv)[(long long)(rbase + r) * 1024 + col] = f2bf(v);
          else
            ((unsigned short*)Cv2)[(long long)(col - 1024) * T_SEQ + (rbase + r)] = f2bf(v);
        }
      }
    }
}

// ---------------------------------------------------------------- RoPE (neox, fp64 angles) on bf16 [T][H*128]
__global__ void rope_bf(unsigned short* __restrict__ buf,
                        const int* __restrict__ positions, int H) {
  const int w = threadIdx.x >> 6, d = threadIdx.x & 63;
  const int gid = blockIdx.x * 4 + w;  // t*H + h
  const int h = gid % H, t = gid / H;
  double inv = exp2(-(double)d * 0.20762050593046014);  // 10000^(-d/64)
  double ang = (double)positions[t] * inv;
  double c = cos(ang), s = sin(ang);
  unsigned short* row = buf + (size_t)t * (H * HDIM) + (size_t)h * HDIM;
  float x1 = bf2f(row[d]), x2 = bf2f(row[d + 64]);
  row[d]      = f2bf((float)((double)x1 * c - (double)x2 * s));
  row[d + 64] = f2bf((float)((double)x2 * c + (double)x1 * s));
}

// ---------------------------------------------------------------- flash attention v4
// One body = 16 q-rows x 64 k-cols for one wave. exp2-domain softmax.
// Common path has NO cross-lane reduces: lane-local max + __any-gated rescale,
// per-lane partial row-sum (reduced once in the epilogue).
__device__ __forceinline__ void attn_body(const unsigned short* __restrict__ Ksb,
                                          const unsigned short* __restrict__ Vsb,
                                          unsigned short* __restrict__ Pw,
                                          const bf16x8 qf[4], f32x4 accO[8],
                                          float mrun[4], float lrun[4],
                                          int qrow0, int kt, int l15, int lg) {
  // S = Q K^T
  f32x4 accS[4];
#pragma unroll
  for (int kc = 0; kc < 4; kc++) accS[kc] = (f32x4){0.f, 0.f, 0.f, 0.f};
#pragma unroll
  for (int kk = 0; kk < 4; kk++)
#pragma unroll
    for (int kc = 0; kc < 4; kc++) {
      int row = kc * 16 + l15;
      bf16x8 b = *(const bf16x8*)(Ksb + row * 128 + (((kk * 4 + lg) ^ (l15 & 7)) * 8));
      accS[kc] = mfma_bf16(qf[kk], b, accS[kc]);
    }

  // scale into log2 domain + causal mask
  const float sc2 = 0.1275174441698669f;  // 1/sqrt(128) * log2(e)
  float pm[4][4];
#pragma unroll
  for (int kc = 0; kc < 4; kc++) {
    int kcol = kt * 64 + kc * 16 + l15;
#pragma unroll
    for (int r = 0; r < 4; r++) {
      float sv = accS[kc][r] * sc2;
      pm[kc][r] = (kcol > qrow0 + lg * 4 + r) ? -3e38f : sv;
    }
  }
  // lane-local max over the 4 cols this lane owns
  float rm[4];
#pragma unroll
  for (int r = 0; r < 4; r++)
    rm[r] = fmaxf(fmaxf(pm[0][r], pm[1][r]), fmaxf(pm[2][r], pm[3][r]));

  // defer-max: only if some lane's local max exceeds mrun+8 do the full reduce+rescale
  int needl = 0;
#pragma unroll
  for (int r = 0; r < 4; r++) needl |= (rm[r] > mrun[r] + 8.f) ? 1 : 0;
  if (__any(needl)) {
#pragma unroll
    for (int off = 1; off < 16; off <<= 1)
#pragma unroll
      for (int r = 0; r < 4; r++) rm[r] = fmaxf(rm[r], __shfl_xor(rm[r], off, 64));
#pragma unroll
    for (int r = 0; r < 4; r++) {
      float mn = fmaxf(mrun[r], rm[r]);
      float corr = exp2f(mrun[r] - mn);
      mrun[r] = mn;
      lrun[r] *= corr;
#pragma unroll
      for (int db = 0; db < 8; db++) accO[db][r] *= corr;
    }
  }

  // P = exp2(pm - mrun); per-lane partial row-sum (no cross-lane reduce here)
  __bf16 pbh[4][4];
#pragma unroll
  for (int kc = 0; kc < 4; kc++)
#pragma unroll
    for (int r = 0; r < 4; r++) {
      float p = exp2f(pm[kc][r] - mrun[r]);
      lrun[r] += p;
      pbh[kc][r] = (__bf16)p;
    }

  // P -> LDS (wave-private, swizzled)
#pragma unroll
  for (int kc = 0; kc < 4; kc++)
#pragma unroll
    for (int r = 0; r < 4; r++) {
      int prow = lg * 4 + r;
      ((__bf16*)Pw)[(prow * 64 + kc * 16 + l15) ^ ((prow & 7) << 3)] = pbh[kc][r];
    }
  asm volatile("s_waitcnt lgkmcnt(0)" ::: "memory");

  // O += P * V
#pragma unroll
  for (int ks = 0; ks < 2; ks++) {
    bf16x8 pa = *(const bf16x8*)(Pw + ((l15 * 64 + ks * 32 + lg * 8) ^ ((l15 & 7) << 3)));
#pragma unroll
    for (int db = 0; db < 8; db++) {
      int row = db * 16 + l15;
      bf16x8 b = *(const bf16x8*)(Vsb + row * 64 + ((ks * 32 + lg * 8) ^ ((l15 & 7) << 3)));
      accO[db] = mfma_bf16(pa, b, accO[db]);
    }
  }
}

// grid: (16, NQH); block 256 = 4 waves x 16 q-rows.
// XCD swizzle maps one kv-head per XCD (chunk = 64 blocks = 4 q-heads).
// Block processes q-tiles jA = 31-bx (long) and jB = bx (short): uniform 33 bodies.
__global__ __launch_bounds__(256) void attn_kernel(const unsigned short* __restrict__ qb,
                                                   const unsigned short* __restrict__ kb,
                                                   const unsigned short* __restrict__ vt,
                                                   unsigned short* __restrict__ ab) {
  __shared__ unsigned short Ks[2][64 * 128];
  __shared__ unsigned short Vs[2][128 * 64];
  __shared__ unsigned short Ps[4][2][16 * 64];

  const int lin = blockIdx.y * gridDim.x + blockIdx.x;  // nwg = 512
  const int swz = (lin & 7) * 64 + (lin >> 3);
  const int bx = swz & 15;
  const int h = swz >> 4;
  const int kvh = h >> 2;
  const int jA = 31 - bx, jB = bx;
  const int q0A = jA * 64, q0B = jB * 64;
  const int t = threadIdx.x, lane = t & 63, w = t >> 6;
  const int l15 = lane & 15, lg = lane >> 4;

  // Q fragments in registers
  bf16x8 qfA[4], qfB[4];
#pragma unroll
  for (int kk = 0; kk < 4; kk++) {
    qfA[kk] = *(const bf16x8*)(qb + (long long)(q0A + w * 16 + l15) * (NQH * HDIM) +
                               h * HDIM + kk * 32 + lg * 8);
    qfB[kk] = *(const bf16x8*)(qb + (long long)(q0B + w * 16 + l15) * (NQH * HDIM) +
                               h * HDIM + kk * 32 + lg * 8);
  }

  f32x4 accA[8], accB[8];
#pragma unroll
  for (int db = 0; db < 8; db++) {
    accA[db] = (f32x4){0.f, 0.f, 0.f, 0.f};
    accB[db] = (f32x4){0.f, 0.f, 0.f, 0.f};
  }
  float mA[4] = {-3e38f, -3e38f, -3e38f, -3e38f}, lA[4] = {0.f, 0.f, 0.f, 0.f};
  float mB[4] = {-3e38f, -3e38f, -3e38f, -3e38f}, lB[4] = {0.f, 0.f, 0.f, 0.f};

  auto stage = [&](int kts, int b) {
#pragma unroll
    for (int s = 0; s < 4; s++) {
      int c = t + s * 256;
      int row = c >> 4, chk = c & 15;
      GLOAD16(kb + (long long)(kts * 64 + row) * (NKVH * HDIM) + kvh * HDIM +
                  ((chk ^ (row & 7)) * 8),
              (char*)(&Ks[b][0]) + (w * 64 + s * 256) * 16);
    }
#pragma unroll
    for (int s = 0; s < 4; s++) {
      int c = t + s * 256;
      int row = c >> 3, chk = c & 7;
      GLOAD16(vt + (long long)(kvh * HDIM + row) * T_SEQ + kts * 64 +
                  ((chk ^ (row & 7)) * 8),
              (char*)(&Vs[b][0]) + (w * 64 + s * 256) * 16);
    }
  };

  const int nt = jA + 1;
  stage(0, 0);
  for (int kt = 0; kt < nt; kt++) {
    const int cur = kt & 1;
    __syncthreads();
    if (kt + 1 < nt) stage(kt + 1, cur ^ 1);
    attn_body(&Ks[cur][0], &Vs[cur][0], &Ps[w][0][0],
              qfA, accA, mA, lA, q0A + w * 16, kt, l15, lg);
    if (kt <= jB)
      attn_body(&Ks[cur][0], &Vs[cur][0], &Ps[w][1][0],
                qfB, accB, mB, lB, q0B + w * 16, kt, l15, lg);
  }

  // epilogue: one cross-lane sum-reduce of the per-lane partial row-sums
#pragma unroll
  for (int off = 1; off < 16; off <<= 1)
#pragma unroll
    for (int r = 0; r < 4; r++) {
      lA[r] += __shfl_xor(lA[r], off, 64);
      lB[r] += __shfl_xor(lB[r], off, 64);
    }
#pragma unroll
  for (int db = 0; db < 8; db++)
#pragma unroll
    for (int r = 0; r < 4; r++) {
      int col = h * HDIM + db * 16 + l15;
      int qrA = q0A + w * 16 + lg * 4 + r;
      int qrB = q0B + w * 16 + lg * 4 + r;
      ((__bf16*)ab)[(long long)qrA * (NQH * HDIM) + col] = (__bf16)(accA[db][r] / lA[r]);
      ((__bf16*)ab)[(long long)qrB * (NQH * HDIM) + col] = (__bf16)(accB[db][r] / lB[r]);
    }
}

// ---------------------------------------------------------------- launch
extern "C" void kernel_launch(void* const* d_in, const int* in_sizes, int n_in,
                              void* d_out, int out_size, void* d_ws, size_t ws_size,
                              hipStream_t stream) {
  const int*   positions = (const int*)d_in[0];
  const float* hs = (const float*)d_in[1];
  const float* wq = (const float*)d_in[2];
  const float* wk = (const float*)d_in[3];
  const float* wv = (const float*)d_in[4];
  const float* wo = (const float*)d_in[5];
  float* out = (float*)d_out;

  // workspace: wt 33.6 + hb/ab 16.8 + qb 16.8 + kb 4.2 + vt 4.2 = 75.5 MB
  const size_t SZ_WT = (size_t)HID * HID * 2;
  const size_t SZ_HB = (size_t)T_SEQ * HID * 2;
  const size_t SZ_QB = (size_t)T_SEQ * NQH * HDIM * 2;
  const size_t SZ_KB = (size_t)T_SEQ * NKVH * HDIM * 2;
  const size_t need = SZ_WT + SZ_HB + SZ_QB + SZ_KB * 2;
  if (ws_size < need) return;  // absmax 4.625 signature

  char* p = (char*)d_ws;
  unsigned short* wt  = (unsigned short*)p; p += SZ_WT;  // wq_t, then wk_t+wv_t, then wo_t
  unsigned short* hb  = (unsigned short*)p; p += SZ_HB;  // hidden bf16; later ab
  unsigned short* qb  = (unsigned short*)p; p += SZ_QB;
  unsigned short* kb  = (unsigned short*)p; p += SZ_KB;
  unsigned short* vtb = (unsigned short*)p; p += SZ_KB;
  unsigned short* ab  = hb;                              // alias: hb dead after KV-GEMM

  conv_f32_bf16<<<(T_SEQ * HID) / 1024, 256, 0, stream>>>(hs, hb);

  // Q projection
  transpose_conv<<<dim3((NQH * HDIM) / 32, HID / 32), 256, 0, stream>>>(wq, wt, HID, NQH * HDIM);
  gemm_bt<0><<<dim3((NQH * HDIM) / 128, T_SEQ / 128), 256, 0, stream>>>(hb, wt, qb, nullptr, T_SEQ, NQH * HDIM, HID);

  // K + V projection fused (N = 2048)
  transpose_conv<<<dim3((NKVH * HDIM) / 32, HID / 32), 256, 0, stream>>>(wk, wt, HID, NKVH * HDIM);
  transpose_conv<<<dim3((NKVH * HDIM) / 32, HID / 32), 256, 0, stream>>>(wv, wt + (size_t)(NKVH * HDIM) * HID, HID, NKVH * HDIM);
  gemm_bt<3><<<dim3((2 * NKVH * HDIM) / 128, T_SEQ / 128), 256, 0, stream>>>(hb, wt, kb, vtb, T_SEQ, 2 * NKVH * HDIM, HID);

  rope_bf<<<(T_SEQ * NQH) / 4, 256, 0, stream>>>(qb, positions, NQH);
  rope_bf<<<(T_SEQ * NKVH) / 4, 256, 0, stream>>>(kb, positions, NKVH);

  attn_kernel<<<dim3(16, NQH), 256, 0, stream>>>(qb, kb, vtb, ab);

  // output projection
  transpose_conv<<<dim3(HID / 32, (NQH * HDIM) / 32), 256, 0, stream>>>(wo, wt, NQH * HDIM, HID);
  gemm_bt<2><<<dim3(HID / 128, T_SEQ / 128), 256, 0, stream>>>(ab, wt, out, nullptr, T_SEQ, HID, NQH * HDIM);
}

// Round 9
// 465.176 us; speedup vs baseline: 15.0604x; 1.0908x over previous
//
#include <hip/hip_runtime.h>

#define T_SEQ  2048
#define HID    4096
#define NQH    32
#define NKVH   8
#define HDIM   128

typedef float  f32x4  __attribute__((ext_vector_type(4)));
typedef __bf16 bf16x8 __attribute__((ext_vector_type(8)));

__device__ __forceinline__ float bf2f(unsigned short u) {
  union { unsigned int i; float f; } v; v.i = ((unsigned int)u) << 16; return v.f;
}
__device__ __forceinline__ unsigned short f2bf(float f) {
  union { float f; unsigned int i; } v; v.f = f;
  unsigned int r = v.i + 0x7fffu + ((v.i >> 16) & 1u);
  return (unsigned short)(r >> 16);
}

__device__ __forceinline__ f32x4 mfma_bf16(bf16x8 a, bf16x8 b, f32x4 c) {
  return __builtin_amdgcn_mfma_f32_16x16x32_bf16(a, b, c, 0, 0, 0);
}

#define GLOAD16(g, l)                                              \
  __builtin_amdgcn_global_load_lds(                                \
      (const __attribute__((address_space(1))) void*)(g),          \
      (__attribute__((address_space(3))) void*)(l), 16, 0, 0)

// ---------------------------------------------------------------- convert
__global__ void conv_f32_bf16(const float* __restrict__ in,
                              unsigned short* __restrict__ out) {
  long long i = ((long long)blockIdx.x * 256 + threadIdx.x) * 4;
  float4 v = *(const float4*)(in + i);
  union { unsigned short u[4]; uint2 p; } o;
  o.u[0] = f2bf(v.x); o.u[1] = f2bf(v.y); o.u[2] = f2bf(v.z); o.u[3] = f2bf(v.w);
  *(uint2*)(out + i) = o.p;
}

// W[K][N] fp32  ->  Wt[N][K] bf16
__global__ void transpose_conv(const float* __restrict__ W,
                               unsigned short* __restrict__ Wt, int K, int N) {
  __shared__ float tile[32][33];
  int n0 = blockIdx.x * 32, k0 = blockIdx.y * 32;
  int tx = threadIdx.x & 31, ty = threadIdx.x >> 5;  // ty 0..7
#pragma unroll
  for (int r = 0; r < 32; r += 8)
    tile[ty + r][tx] = W[(long long)(k0 + ty + r) * N + n0 + tx];
  __syncthreads();
#pragma unroll
  for (int r = 0; r < 32; r += 8)
    Wt[(long long)(n0 + ty + r) * K + k0 + tx] = f2bf(tile[tx][ty + r]);
}

// ---------------------------------------------------------------- GEMM (m97 structure + XCD swizzle), BM=128
// C[M,N] = A[M,K](bf16,row-major) * Bt[N,K](bf16,row-major)^T
// EPI: 0 = bf16 row-major out; 2 = fp32 row-major out
template <int EPI>
__global__ __launch_bounds__(256) void gemm_bt(const unsigned short* __restrict__ A,
                                               const unsigned short* __restrict__ Bt,
                                               void* __restrict__ Cv,
                                               int M, int N, int K) {
  __shared__ unsigned short As[128 * 32];
  __shared__ unsigned short Bs[128 * 32];
  const int lin = blockIdx.y * gridDim.x + blockIdx.x;
  const int cpx = (gridDim.x * gridDim.y) >> 3;
  const int swz = (lin & 7) * cpx + (lin >> 3);
  const int bx = swz % gridDim.x, by = swz / gridDim.x;

  const int t = threadIdx.x;
  const int lane = t & 63, w = t >> 6;
  const int wr = w >> 1, wc = w & 1;
  const int l15 = lane & 15, lg = lane >> 4;
  const int m0 = by * 128, n0 = bx * 128;

  f32x4 acc[4][4];
#pragma unroll
  for (int i = 0; i < 4; i++)
#pragma unroll
    for (int j = 0; j < 4; j++) acc[i][j] = (f32x4){0.f, 0.f, 0.f, 0.f};

  const int c0 = t, c1 = t + 256;  // 16B chunks (row = c>>2, sub = c&3)

  for (int kt = 0; kt < K; kt += 32) {
    __syncthreads();
    GLOAD16(A + (long long)(m0 + (c0 >> 2)) * K + kt + (c0 & 3) * 8,
            (char*)As + (w * 64) * 16);
    GLOAD16(A + (long long)(m0 + (c1 >> 2)) * K + kt + (c1 & 3) * 8,
            (char*)As + (w * 64 + 256) * 16);
    GLOAD16(Bt + (long long)(n0 + (c0 >> 2)) * K + kt + (c0 & 3) * 8,
            (char*)Bs + (w * 64) * 16);
    GLOAD16(Bt + (long long)(n0 + (c1 >> 2)) * K + kt + (c1 & 3) * 8,
            (char*)Bs + (w * 64 + 256) * 16);
    __syncthreads();

    bf16x8 af[4], bfr[4];
#pragma unroll
    for (int mi = 0; mi < 4; mi++)
      af[mi] = *(const bf16x8*)(As + (wr * 64 + mi * 16 + l15) * 32 + lg * 8);
#pragma unroll
    for (int ni = 0; ni < 4; ni++)
      bfr[ni] = *(const bf16x8*)(Bs + (wc * 64 + ni * 16 + l15) * 32 + lg * 8);
#pragma unroll
    for (int mi = 0; mi < 4; mi++)
#pragma unroll
      for (int ni = 0; ni < 4; ni++)
        acc[mi][ni] = mfma_bf16(af[mi], bfr[ni], acc[mi][ni]);
  }

  const int row0 = m0 + wr * 64, col0 = n0 + wc * 64;
#pragma unroll
  for (int mi = 0; mi < 4; mi++)
#pragma unroll
    for (int ni = 0; ni < 4; ni++) {
      int rbase = row0 + mi * 16 + lg * 4;
      int col = col0 + ni * 16 + l15;
#pragma unroll
      for (int r = 0; r < 4; r++) {
        float v = acc[mi][ni][r];
        if (EPI == 0)
          ((unsigned short*)Cv)[(long long)(rbase + r) * N + col] = f2bf(v);
        else
          ((float*)Cv)[(long long)(rbase + r) * N + col] = v;
      }
    }
}

// ---------------------------------------------------------------- KV GEMM, BM=64 (512 blocks -> 2/CU)
// A[2048][4096] * Bt[2048][4096]^T; cols<1024 -> kb bf16 [2048][1024];
// cols>=1024 -> vtb transposed bf16 [1024][2048]
__global__ __launch_bounds__(256) void gemm_kv64(const unsigned short* __restrict__ A,
                                                 const unsigned short* __restrict__ Bt,
                                                 unsigned short* __restrict__ Ckv,
                                                 unsigned short* __restrict__ Cvt) {
  __shared__ unsigned short As[64 * 32];
  __shared__ unsigned short Bs[128 * 32];
  const int lin = blockIdx.y * gridDim.x + blockIdx.x;  // grid (16,32) = 512
  const int swz = (lin & 7) * 64 + (lin >> 3);
  const int bx = swz & 15, by = swz >> 4;

  const int t = threadIdx.x;
  const int lane = t & 63, w = t >> 6;
  const int wr = w >> 1, wc = w & 1;
  const int l15 = lane & 15, lg = lane >> 4;
  const int m0 = by * 64, n0 = bx * 128;
  const int K = HID, M = T_SEQ;

  f32x4 acc[2][4];
#pragma unroll
  for (int i = 0; i < 2; i++)
#pragma unroll
    for (int j = 0; j < 4; j++) acc[i][j] = (f32x4){0.f, 0.f, 0.f, 0.f};

  const int c0 = t, c1 = t + 256;

  for (int kt = 0; kt < K; kt += 32) {
    __syncthreads();
    GLOAD16(A + (long long)(m0 + (c0 >> 2)) * K + kt + (c0 & 3) * 8,
            (char*)As + (w * 64) * 16);
    GLOAD16(Bt + (long long)(n0 + (c0 >> 2)) * K + kt + (c0 & 3) * 8,
            (char*)Bs + (w * 64) * 16);
    GLOAD16(Bt + (long long)(n0 + (c1 >> 2)) * K + kt + (c1 & 3) * 8,
            (char*)Bs + (w * 64 + 256) * 16);
    __syncthreads();

    bf16x8 af[2], bfr[4];
#pragma unroll
    for (int mi = 0; mi < 2; mi++)
      af[mi] = *(const bf16x8*)(As + (wr * 32 + mi * 16 + l15) * 32 + lg * 8);
#pragma unroll
    for (int ni = 0; ni < 4; ni++)
      bfr[ni] = *(const bf16x8*)(Bs + (wc * 64 + ni * 16 + l15) * 32 + lg * 8);
#pragma unroll
    for (int mi = 0; mi < 2; mi++)
#pragma unroll
      for (int ni = 0; ni < 4; ni++)
        acc[mi][ni] = mfma_bf16(af[mi], bfr[ni], acc[mi][ni]);
  }

  const int row0 = m0 + wr * 32, col0 = n0 + wc * 64;
#pragma unroll
  for (int mi = 0; mi < 2; mi++)
#pragma unroll
    for (int ni = 0; ni < 4; ni++) {
      int rbase = row0 + mi * 16 + lg * 4;
      int col = col0 + ni * 16 + l15;
#pragma unroll
      for (int r = 0; r < 4; r++) {
        float v = acc[mi][ni][r];
        if (col < 1024)
          Ckv[(long long)(rbase + r) * 1024 + col] = f2bf(v);
        else
          Cvt[(long long)(col - 1024) * T_SEQ + (rbase + r)] = f2bf(v);
      }
    }
}

// ---------------------------------------------------------------- RoPE (neox, fp64 angles), fused q+k
__global__ void rope_all(unsigned short* __restrict__ qb,
                         unsigned short* __restrict__ kb,
                         const int* __restrict__ positions) {
  const int w = threadIdx.x >> 6, d = threadIdx.x & 63;
  const int gid = blockIdx.x * 4 + w;
  unsigned short* row;
  int t;
  if (gid < T_SEQ * NQH) {
    int h = gid & (NQH - 1); t = gid >> 5;
    row = qb + (size_t)t * (NQH * HDIM) + (size_t)h * HDIM;
  } else {
    int g = gid - T_SEQ * NQH;
    int h = g & (NKVH - 1); t = g >> 3;
    row = kb + (size_t)t * (NKVH * HDIM) + (size_t)h * HDIM;
  }
  double inv = exp2(-(double)d * 0.20762050593046014);  // 10000^(-d/64)
  double ang = (double)positions[t] * inv;
  double c = cos(ang), s = sin(ang);
  float x1 = bf2f(row[d]), x2 = bf2f(row[d + 64]);
  row[d]      = f2bf((float)((double)x1 * c - (double)x2 * s));
  row[d + 64] = f2bf((float)((double)x2 * c + (double)x1 * s));
}

// ---------------------------------------------------------------- flash attention v5
// grid (32, 32) = 1024 blocks; block = 4 waves x 16 q-rows = one 64-row q-tile.
// KVBLK=32, LDS 36KB (-> 3-4 blocks/CU). Longest-first + XCD swizzle (1 kv-head/XCD).
__global__ __launch_bounds__(256) void attn_kernel(const unsigned short* __restrict__ qb,
                                                   const unsigned short* __restrict__ kb,
                                                   const unsigned short* __restrict__ vt,
                                                   unsigned short* __restrict__ ab) {
  __shared__ unsigned short Ks[2][32 * 128];
  __shared__ unsigned short Vs[2][128 * 32];
  __shared__ unsigned short Ps[4][16 * 32];

  const int lin = blockIdx.y * gridDim.x + blockIdx.x;  // 0..1023
  const int swz = (lin & 7) * 128 + (lin >> 3);
  const int bx = swz & 31;          // 0..31 within XCD chunk
  const int h  = swz >> 5;          // q-head; 4 consecutive heads per XCD
  const int kvh = h >> 2;
  const int j  = 31 - bx;           // longest first
  const int q0 = j * 64;
  const int t = threadIdx.x, lane = t & 63, w = t >> 6;
  const int l15 = lane & 15, lg = lane >> 4;

  // Q fragments in registers
  bf16x8 qf[4];
#pragma unroll
  for (int kk = 0; kk < 4; kk++)
    qf[kk] = *(const bf16x8*)(qb + (long long)(q0 + w * 16 + l15) * (NQH * HDIM) +
                              h * HDIM + kk * 32 + lg * 8);

  f32x4 accO[8];
#pragma unroll
  for (int db = 0; db < 8; db++) accO[db] = (f32x4){0.f, 0.f, 0.f, 0.f};
  float mrun[4] = {-3e38f, -3e38f, -3e38f, -3e38f};
  float lrun[4] = {0.f, 0.f, 0.f, 0.f};

  auto stage = [&](int kts, int b) {
    // K tile 32x128: 512 chunks, swizzled source (chunk ^= row&7)
#pragma unroll
    for (int s = 0; s < 2; s++) {
      int c = t + s * 256;
      int row = c >> 4, chk = c & 15;
      GLOAD16(kb + (long long)(kts * 32 + row) * (NKVH * HDIM) + kvh * HDIM +
                  ((chk ^ (row & 7)) * 8),
              (char*)(&Ks[b][0]) + (w * 64 + s * 256) * 16);
    }
    // Vt tile 128x32: 512 chunks, swizzled source (chunk ^= row&3)
#pragma unroll
    for (int s = 0; s < 2; s++) {
      int c = t + s * 256;
      int row = c >> 2, chk = c & 3;
      GLOAD16(vt + (long long)(kvh * HDIM + row) * T_SEQ + kts * 32 +
                  ((chk ^ (row & 3)) * 8),
              (char*)(&Vs[b][0]) + (w * 64 + s * 256) * 16);
    }
  };

  const int nt = 2 * (j + 1);
  const int qrowmax = q0 + w * 16 + 15;
  stage(0, 0);
  for (int kt = 0; kt < nt; kt++) {
    const int cur = kt & 1;
    __syncthreads();
    if (kt + 1 < nt) stage(kt + 1, cur ^ 1);
    if (kt * 32 > qrowmax) continue;  // fully-masked tile for this wave (no barrier below)

    // S = Q K^T : 16 q-rows x 32 k-cols
    f32x4 accS[2];
    accS[0] = (f32x4){0.f, 0.f, 0.f, 0.f};
    accS[1] = (f32x4){0.f, 0.f, 0.f, 0.f};
#pragma unroll
    for (int kk = 0; kk < 4; kk++)
#pragma unroll
      for (int kc = 0; kc < 2; kc++) {
        int row = kc * 16 + l15;
        bf16x8 b = *(const bf16x8*)(&Ks[cur][0] + row * 128 + (((kk * 4 + lg) ^ (l15 & 7)) * 8));
        accS[kc] = mfma_bf16(qf[kk], b, accS[kc]);
      }

    // scale (log2 domain) + causal mask
    const float sc2 = 0.1275174441698669f;  // 1/sqrt(128) * log2(e)
    float pm[2][4];
#pragma unroll
    for (int kc = 0; kc < 2; kc++) {
      int kcol = kt * 32 + kc * 16 + l15;
#pragma unroll
      for (int r = 0; r < 4; r++) {
        float sv = accS[kc][r] * sc2;
        pm[kc][r] = (kcol > q0 + w * 16 + lg * 4 + r) ? -3e38f : sv;
      }
    }
    // lane-local max; __any-gated full reduce + rescale (defer-max THR=8)
    float rm[4];
#pragma unroll
    for (int r = 0; r < 4; r++) rm[r] = fmaxf(pm[0][r], pm[1][r]);
    int needl = 0;
#pragma unroll
    for (int r = 0; r < 4; r++) needl |= (rm[r] > mrun[r] + 8.f) ? 1 : 0;
    if (__any(needl)) {
#pragma unroll
      for (int off = 1; off < 16; off <<= 1)
#pragma unroll
        for (int r = 0; r < 4; r++) rm[r] = fmaxf(rm[r], __shfl_xor(rm[r], off, 64));
#pragma unroll
      for (int r = 0; r < 4; r++) {
        float mn = fmaxf(mrun[r], rm[r]);
        float corr = exp2f(mrun[r] - mn);
        mrun[r] = mn;
        lrun[r] *= corr;
#pragma unroll
        for (int db = 0; db < 8; db++) accO[db][r] *= corr;
      }
    }

    // P = exp2(pm - mrun); per-lane partial row-sum
    __bf16 pbh[2][4];
#pragma unroll
    for (int kc = 0; kc < 2; kc++)
#pragma unroll
      for (int r = 0; r < 4; r++) {
        float p = exp2f(pm[kc][r] - mrun[r]);
        lrun[r] += p;
        pbh[kc][r] = (__bf16)p;
      }

    // P -> LDS (wave-private [16][32], chunk XOR (row&3))
    unsigned short* Pw = &Ps[w][0];
#pragma unroll
    for (int kc = 0; kc < 2; kc++)
#pragma unroll
      for (int r = 0; r < 4; r++) {
        int prow = lg * 4 + r;
        ((__bf16*)Pw)[(prow * 32 + kc * 16 + l15) ^ ((prow & 3) << 3)] = pbh[kc][r];
      }
    asm volatile("s_waitcnt lgkmcnt(0)" ::: "memory");

    // O += P * V
    bf16x8 pa = *(const bf16x8*)(Pw + ((l15 * 32 + lg * 8) ^ ((l15 & 3) << 3)));
#pragma unroll
    for (int db = 0; db < 8; db++) {
      int vrow = db * 16 + l15;
      bf16x8 b = *(const bf16x8*)(&Vs[cur][0] + vrow * 32 + ((lg ^ (vrow & 3)) * 8));
      accO[db] = mfma_bf16(pa, b, accO[db]);
    }
  }

  // epilogue: reduce per-lane partial row-sums (within 16-lane groups), write
#pragma unroll
  for (int off = 1; off < 16; off <<= 1)
#pragma unroll
    for (int r = 0; r < 4; r++) lrun[r] += __shfl_xor(lrun[r], off, 64);
#pragma unroll
  for (int db = 0; db < 8; db++)
#pragma unroll
    for (int r = 0; r < 4; r++) {
      int qr = q0 + w * 16 + lg * 4 + r;
      int col = h * HDIM + db * 16 + l15;
      ((__bf16*)ab)[(long long)qr * (NQH * HDIM) + col] = (__bf16)(accO[db][r] / lrun[r]);
    }
}

// ---------------------------------------------------------------- launch
extern "C" void kernel_launch(void* const* d_in, const int* in_sizes, int n_in,
                              void* d_out, int out_size, void* d_ws, size_t ws_size,
                              hipStream_t stream) {
  const int*   positions = (const int*)d_in[0];
  const float* hs = (const float*)d_in[1];
  const float* wq = (const float*)d_in[2];
  const float* wk = (const float*)d_in[3];
  const float* wv = (const float*)d_in[4];
  const float* wo = (const float*)d_in[5];
  float* out = (float*)d_out;

  // workspace: wt 33.6 + hb/ab 16.8 + qb 16.8 + kb 4.2 + vt 4.2 = 75.5 MB
  const size_t SZ_WT = (size_t)HID * HID * 2;
  const size_t SZ_HB = (size_t)T_SEQ * HID * 2;
  const size_t SZ_QB = (size_t)T_SEQ * NQH * HDIM * 2;
  const size_t SZ_KB = (size_t)T_SEQ * NKVH * HDIM * 2;
  const size_t need = SZ_WT + SZ_HB + SZ_QB + SZ_KB * 2;
  if (ws_size < need) return;  // absmax 4.625 signature

  char* p = (char*)d_ws;
  unsigned short* wt  = (unsigned short*)p; p += SZ_WT;  // wq_t, then wk_t+wv_t, then wo_t
  unsigned short* hb  = (unsigned short*)p; p += SZ_HB;  // hidden bf16; later ab
  unsigned short* qb  = (unsigned short*)p; p += SZ_QB;
  unsigned short* kb  = (unsigned short*)p; p += SZ_KB;
  unsigned short* vtb = (unsigned short*)p; p += SZ_KB;
  unsigned short* ab  = hb;                              // alias: hb dead after KV-GEMM

  conv_f32_bf16<<<(T_SEQ * HID) / 1024, 256, 0, stream>>>(hs, hb);

  // Q projection
  transpose_conv<<<dim3((NQH * HDIM) / 32, HID / 32), 256, 0, stream>>>(wq, wt, HID, NQH * HDIM);
  gemm_bt<0><<<dim3((NQH * HDIM) / 128, T_SEQ / 128), 256, 0, stream>>>(hb, wt, qb, T_SEQ, NQH * HDIM, HID);

  // K + V projection fused (N = 2048), BM=64
  transpose_conv<<<dim3((NKVH * HDIM) / 32, HID / 32), 256, 0, stream>>>(wk, wt, HID, NKVH * HDIM);
  transpose_conv<<<dim3((NKVH * HDIM) / 32, HID / 32), 256, 0, stream>>>(wv, wt + (size_t)(NKVH * HDIM) * HID, HID, NKVH * HDIM);
  gemm_kv64<<<dim3(16, 32), 256, 0, stream>>>(hb, wt, kb, vtb);

  rope_all<<<(T_SEQ * (NQH + NKVH)) / 4, 256, 0, stream>>>(qb, kb, positions);

  attn_kernel<<<dim3(32, 32), 256, 0, stream>>>(qb, kb, vtb, ab);

  // output projection
  transpose_conv<<<dim3(HID / 32, (NQH * HDIM) / 32), 256, 0, stream>>>(wo, wt, NQH * HDIM, HID);
  gemm_bt<2><<<dim3(HID / 128, T_SEQ / 128), 256, 0, stream>>>(ab, wt, out, T_SEQ, HID, NQH * HDIM);
}

// Round 10
// 455.276 us; speedup vs baseline: 15.3879x; 1.0217x over previous
//
#include <hip/hip_runtime.h>

#define T_SEQ  2048
#define HID    4096
#define NQH    32
#define NKVH   8
#define HDIM   128

typedef float  f32x4  __attribute__((ext_vector_type(4)));
typedef __bf16 bf16x8 __attribute__((ext_vector_type(8)));

__device__ __forceinline__ float bf2f(unsigned short u) {
  union { unsigned int i; float f; } v; v.i = ((unsigned int)u) << 16; return v.f;
}
__device__ __forceinline__ unsigned short f2bf(float f) {
  union { float f; unsigned int i; } v; v.f = f;
  unsigned int r = v.i + 0x7fffu + ((v.i >> 16) & 1u);
  return (unsigned short)(r >> 16);
}

__device__ __forceinline__ f32x4 mfma_bf16(bf16x8 a, bf16x8 b, f32x4 c) {
  return __builtin_amdgcn_mfma_f32_16x16x32_bf16(a, b, c, 0, 0, 0);
}

#define GLOAD16(g, l)                                              \
  __builtin_amdgcn_global_load_lds(                                \
      (const __attribute__((address_space(1))) void*)(g),          \
      (__attribute__((address_space(3))) void*)(l), 16, 0, 0)

// ---------------------------------------------------------------- convert
__global__ void conv_f32_bf16(const float* __restrict__ in,
                              unsigned short* __restrict__ out) {
  long long i = ((long long)blockIdx.x * 256 + threadIdx.x) * 4;
  float4 v = *(const float4*)(in + i);
  union { unsigned short u[4]; uint2 p; } o;
  o.u[0] = f2bf(v.x); o.u[1] = f2bf(v.y); o.u[2] = f2bf(v.z); o.u[3] = f2bf(v.w);
  *(uint2*)(out + i) = o.p;
}

// W[K][N] fp32  ->  Wt[N][K] bf16
__global__ void transpose_conv(const float* __restrict__ W,
                               unsigned short* __restrict__ Wt, int K, int N) {
  __shared__ float tile[32][33];
  int n0 = blockIdx.x * 32, k0 = blockIdx.y * 32;
  int tx = threadIdx.x & 31, ty = threadIdx.x >> 5;
#pragma unroll
  for (int r = 0; r < 32; r += 8)
    tile[ty + r][tx] = W[(long long)(k0 + ty + r) * N + n0 + tx];
  __syncthreads();
#pragma unroll
  for (int r = 0; r < 32; r += 8)
    Wt[(long long)(n0 + ty + r) * K + k0 + tx] = f2bf(tile[tx][ty + r]);
}

// fused wk+wv transpose (z = 0 -> wk, z = 1 -> wv); dst contiguous halves of wt
__global__ void transpose_conv_kv(const float* __restrict__ Wk,
                                  const float* __restrict__ Wv,
                                  unsigned short* __restrict__ Wt) {
  __shared__ float tile[32][33];
  const int N = NKVH * HDIM, K = HID;
  const float* W = blockIdx.z ? Wv : Wk;
  unsigned short* dst = Wt + (size_t)blockIdx.z * N * K;
  int n0 = blockIdx.x * 32, k0 = blockIdx.y * 32;
  int tx = threadIdx.x & 31, ty = threadIdx.x >> 5;
#pragma unroll
  for (int r = 0; r < 32; r += 8)
    tile[ty + r][tx] = W[(long long)(k0 + ty + r) * N + n0 + tx];
  __syncthreads();
#pragma unroll
  for (int r = 0; r < 32; r += 8)
    dst[(long long)(n0 + ty + r) * K + k0 + tx] = f2bf(tile[tx][ty + r]);
}

// ---------------------------------------------------------------- GEMM (m97 structure + XCD swizzle), BM=128
// EPI: 0 = bf16 row-major out; 2 = fp32 row-major out
template <int EPI>
__global__ __launch_bounds__(256) void gemm_bt(const unsigned short* __restrict__ A,
                                               const unsigned short* __restrict__ Bt,
                                               void* __restrict__ Cv,
                                               int M, int N, int K) {
  __shared__ unsigned short As[128 * 32];
  __shared__ unsigned short Bs[128 * 32];
  const int lin = blockIdx.y * gridDim.x + blockIdx.x;
  const int cpx = (gridDim.x * gridDim.y) >> 3;
  const int swz = (lin & 7) * cpx + (lin >> 3);
  const int bx = swz % gridDim.x, by = swz / gridDim.x;

  const int t = threadIdx.x;
  const int lane = t & 63, w = t >> 6;
  const int wr = w >> 1, wc = w & 1;
  const int l15 = lane & 15, lg = lane >> 4;
  const int m0 = by * 128, n0 = bx * 128;

  f32x4 acc[4][4];
#pragma unroll
  for (int i = 0; i < 4; i++)
#pragma unroll
    for (int j = 0; j < 4; j++) acc[i][j] = (f32x4){0.f, 0.f, 0.f, 0.f};

  const int c0 = t, c1 = t + 256;

  for (int kt = 0; kt < K; kt += 32) {
    __syncthreads();
    GLOAD16(A + (long long)(m0 + (c0 >> 2)) * K + kt + (c0 & 3) * 8,
            (char*)As + (w * 64) * 16);
    GLOAD16(A + (long long)(m0 + (c1 >> 2)) * K + kt + (c1 & 3) * 8,
            (char*)As + (w * 64 + 256) * 16);
    GLOAD16(Bt + (long long)(n0 + (c0 >> 2)) * K + kt + (c0 & 3) * 8,
            (char*)Bs + (w * 64) * 16);
    GLOAD16(Bt + (long long)(n0 + (c1 >> 2)) * K + kt + (c1 & 3) * 8,
            (char*)Bs + (w * 64 + 256) * 16);
    __syncthreads();

    bf16x8 af[4], bfr[4];
#pragma unroll
    for (int mi = 0; mi < 4; mi++)
      af[mi] = *(const bf16x8*)(As + (wr * 64 + mi * 16 + l15) * 32 + lg * 8);
#pragma unroll
    for (int ni = 0; ni < 4; ni++)
      bfr[ni] = *(const bf16x8*)(Bs + (wc * 64 + ni * 16 + l15) * 32 + lg * 8);
#pragma unroll
    for (int mi = 0; mi < 4; mi++)
#pragma unroll
      for (int ni = 0; ni < 4; ni++)
        acc[mi][ni] = mfma_bf16(af[mi], bfr[ni], acc[mi][ni]);
  }

  const int row0 = m0 + wr * 64, col0 = n0 + wc * 64;
#pragma unroll
  for (int mi = 0; mi < 4; mi++)
#pragma unroll
    for (int ni = 0; ni < 4; ni++) {
      int rbase = row0 + mi * 16 + lg * 4;
      int col = col0 + ni * 16 + l15;
#pragma unroll
      for (int r = 0; r < 4; r++) {
        float v = acc[mi][ni][r];
        if (EPI == 0)
          ((unsigned short*)Cv)[(long long)(rbase + r) * N + col] = f2bf(v);
        else
          ((float*)Cv)[(long long)(rbase + r) * N + col] = v;
      }
    }
}

// ---------------------------------------------------------------- KV GEMM, BM=64 (512 blocks -> 2/CU)
// cols<1024 -> kb [2048][1024]; cols>=1024 -> vtb [1024][2048] via LDS-transpose epilogue
__global__ __launch_bounds__(256) void gemm_kv64(const unsigned short* __restrict__ A,
                                                 const unsigned short* __restrict__ Bt,
                                                 unsigned short* __restrict__ Ckv,
                                                 unsigned short* __restrict__ Cvt) {
  __shared__ unsigned short As[64 * 32];
  __shared__ unsigned short Bs[128 * 32];
  __shared__ unsigned short Tt[128 * 64];  // V transpose bounce
  const int lin = blockIdx.y * gridDim.x + blockIdx.x;  // grid (16,32) = 512
  const int swz = (lin & 7) * 64 + (lin >> 3);
  const int bx = swz & 15, by = swz >> 4;

  const int t = threadIdx.x;
  const int lane = t & 63, w = t >> 6;
  const int wr = w >> 1, wc = w & 1;
  const int l15 = lane & 15, lg = lane >> 4;
  const int m0 = by * 64, n0 = bx * 128;
  const int K = HID;

  f32x4 acc[2][4];
#pragma unroll
  for (int i = 0; i < 2; i++)
#pragma unroll
    for (int j = 0; j < 4; j++) acc[i][j] = (f32x4){0.f, 0.f, 0.f, 0.f};

  const int c0 = t, c1 = t + 256;

  for (int kt = 0; kt < K; kt += 32) {
    __syncthreads();
    GLOAD16(A + (long long)(m0 + (c0 >> 2)) * K + kt + (c0 & 3) * 8,
            (char*)As + (w * 64) * 16);
    GLOAD16(Bt + (long long)(n0 + (c0 >> 2)) * K + kt + (c0 & 3) * 8,
            (char*)Bs + (w * 64) * 16);
    GLOAD16(Bt + (long long)(n0 + (c1 >> 2)) * K + kt + (c1 & 3) * 8,
            (char*)Bs + (w * 64 + 256) * 16);
    __syncthreads();

    bf16x8 af[2], bfr[4];
#pragma unroll
    for (int mi = 0; mi < 2; mi++)
      af[mi] = *(const bf16x8*)(As + (wr * 32 + mi * 16 + l15) * 32 + lg * 8);
#pragma unroll
    for (int ni = 0; ni < 4; ni++)
      bfr[ni] = *(const bf16x8*)(Bs + (wc * 64 + ni * 16 + l15) * 32 + lg * 8);
#pragma unroll
    for (int mi = 0; mi < 2; mi++)
#pragma unroll
      for (int ni = 0; ni < 4; ni++)
        acc[mi][ni] = mfma_bf16(af[mi], bfr[ni], acc[mi][ni]);
  }

  const int row0 = m0 + wr * 32, col0 = n0 + wc * 64;
  if (n0 < 1024) {
    // K half: direct bf16 row-major writes
#pragma unroll
    for (int mi = 0; mi < 2; mi++)
#pragma unroll
      for (int ni = 0; ni < 4; ni++) {
        int rbase = row0 + mi * 16 + lg * 4;
        int col = col0 + ni * 16 + l15;
#pragma unroll
        for (int r = 0; r < 4; r++)
          Ckv[(long long)(rbase + r) * 1024 + col] = f2bf(acc[mi][ni][r]);
      }
  } else {
    // V half: transpose via LDS, coalesced writes to Cvt[1024][2048]
#pragma unroll
    for (int mi = 0; mi < 2; mi++)
#pragma unroll
      for (int ni = 0; ni < 4; ni++) {
        int nloc = wc * 64 + ni * 16 + l15;
#pragma unroll
        for (int r = 0; r < 4; r++) {
          int mloc = wr * 32 + mi * 16 + lg * 4 + r;
          Tt[nloc * 64 + (mloc ^ ((nloc & 7) << 3))] = f2bf(acc[mi][ni][r]);
        }
      }
    __syncthreads();
    const int nloc = t >> 1;
#pragma unroll
    for (int cc = 0; cc < 4; cc++) {
      int ci = (t & 1) * 4 + cc;
      int sc = ci ^ (nloc & 7);
      uint4 v = *(const uint4*)(Tt + nloc * 64 + sc * 8);
      *(uint4*)(Cvt + (long long)(n0 - 1024 + nloc) * T_SEQ + m0 + ci * 8) = v;
    }
  }
}

// ---------------------------------------------------------------- RoPE (neox, fp64 angles), fused q+k
// Q rows additionally pre-scaled by 1/sqrt(128)*log2(e) (softmax scale folded in)
__global__ void rope_all(unsigned short* __restrict__ qb,
                         unsigned short* __restrict__ kb,
                         const int* __restrict__ positions) {
  const int w = threadIdx.x >> 6, d = threadIdx.x & 63;
  const int gid = blockIdx.x * 4 + w;
  unsigned short* row;
  int t;
  bool isq;
  if (gid < T_SEQ * NQH) {
    int h = gid & (NQH - 1); t = gid >> 5;
    row = qb + (size_t)t * (NQH * HDIM) + (size_t)h * HDIM;
    isq = true;
  } else {
    int g = gid - T_SEQ * NQH;
    int h = g & (NKVH - 1); t = g >> 3;
    row = kb + (size_t)t * (NKVH * HDIM) + (size_t)h * HDIM;
    isq = false;
  }
  double inv = exp2(-(double)d * 0.20762050593046014);  // 10000^(-d/64)
  double ang = (double)positions[t] * inv;
  double c = cos(ang), s = sin(ang);
  if (isq) { c *= 0.12751744416986895; s *= 0.12751744416986895; }
  float x1 = bf2f(row[d]), x2 = bf2f(row[d + 64]);
  row[d]      = f2bf((float)((double)x1 * c - (double)x2 * s));
  row[d + 64] = f2bf((float)((double)x2 * c + (double)x1 * s));
}

// ---------------------------------------------------------------- flash attention v6
// grid (32,32) = 1024 blocks; block = 4 waves x 16 q-rows = one 64-row q-tile.
// KVBLK=64, SINGLE-buffered (40KB LDS -> 4 blocks/CU); diagonal-only masking;
// Q pre-scaled (log2 domain); setprio around MFMA; XCD swizzle (1 kv-head/XCD).
__global__ __launch_bounds__(256) void attn_kernel(const unsigned short* __restrict__ qb,
                                                   const unsigned short* __restrict__ kb,
                                                   const unsigned short* __restrict__ vt,
                                                   unsigned short* __restrict__ ab) {
  __shared__ unsigned short Ks[64 * 128];
  __shared__ unsigned short Vs[128 * 64];
  __shared__ unsigned short Ps[4][16 * 64];

  const int lin = blockIdx.y * gridDim.x + blockIdx.x;  // 0..1023
  const int swz = (lin & 7) * 128 + (lin >> 3);
  const int bx = swz & 31;
  const int h  = swz >> 5;
  const int kvh = h >> 2;
  const int j  = 31 - bx;  // longest first
  const int q0 = j * 64;
  const int t = threadIdx.x, lane = t & 63, w = t >> 6;
  const int l15 = lane & 15, lg = lane >> 4;

  bf16x8 qf[4];
#pragma unroll
  for (int kk = 0; kk < 4; kk++)
    qf[kk] = *(const bf16x8*)(qb + (long long)(q0 + w * 16 + l15) * (NQH * HDIM) +
                              h * HDIM + kk * 32 + lg * 8);

  f32x4 accO[8];
#pragma unroll
  for (int db = 0; db < 8; db++) accO[db] = (f32x4){0.f, 0.f, 0.f, 0.f};
  float mrun[4] = {-3e38f, -3e38f, -3e38f, -3e38f};
  float lrun[4] = {0.f, 0.f, 0.f, 0.f};

  const int nt = j + 1;
  for (int kt = 0; kt < nt; kt++) {
    __syncthreads();  // previous tile fully consumed
    // K tile 64x128: 1024 chunks, swizzled source (chunk ^= row&7)
#pragma unroll
    for (int s = 0; s < 4; s++) {
      int c = t + s * 256;
      int row = c >> 4, chk = c & 15;
      GLOAD16(kb + (long long)(kt * 64 + row) * (NKVH * HDIM) + kvh * HDIM +
                  ((chk ^ (row & 7)) * 8),
              (char*)Ks + (w * 64 + s * 256) * 16);
    }
    // Vt tile 128x64: 1024 chunks, swizzled source
#pragma unroll
    for (int s = 0; s < 4; s++) {
      int c = t + s * 256;
      int row = c >> 3, chk = c & 7;
      GLOAD16(vt + (long long)(kvh * HDIM + row) * T_SEQ + kt * 64 +
                  ((chk ^ (row & 7)) * 8),
              (char*)Vs + (w * 64 + s * 256) * 16);
    }
    __syncthreads();  // drains vmcnt -> tile ready

    // S = Q K^T : 16 q-rows x 64 k-cols (already log2-scaled via Q)
    f32x4 accS[4];
#pragma unroll
    for (int kc = 0; kc < 4; kc++) accS[kc] = (f32x4){0.f, 0.f, 0.f, 0.f};
    __builtin_amdgcn_s_setprio(1);
#pragma unroll
    for (int kk = 0; kk < 4; kk++)
#pragma unroll
      for (int kc = 0; kc < 4; kc++) {
        int row = kc * 16 + l15;
        bf16x8 b = *(const bf16x8*)(Ks + row * 128 + (((kk * 4 + lg) ^ (l15 & 7)) * 8));
        accS[kc] = mfma_bf16(qf[kk], b, accS[kc]);
      }
    __builtin_amdgcn_s_setprio(0);

    // causal mask only on the diagonal tile
    float pm[4][4];
    if (kt == j) {
#pragma unroll
      for (int kc = 0; kc < 4; kc++) {
        int kcl = kc * 16 + l15;  // local col
#pragma unroll
        for (int r = 0; r < 4; r++)
          pm[kc][r] = (kcl > w * 16 + lg * 4 + r) ? -3e38f : accS[kc][r];
      }
    } else {
#pragma unroll
      for (int kc = 0; kc < 4; kc++)
#pragma unroll
        for (int r = 0; r < 4; r++) pm[kc][r] = accS[kc][r];
    }

    // lane-local max; __any-gated full reduce + rescale (defer-max THR=8)
    float rm[4];
#pragma unroll
    for (int r = 0; r < 4; r++)
      rm[r] = fmaxf(fmaxf(pm[0][r], pm[1][r]), fmaxf(pm[2][r], pm[3][r]));
    int needl = 0;
#pragma unroll
    for (int r = 0; r < 4; r++) needl |= (rm[r] > mrun[r] + 8.f) ? 1 : 0;
    if (__any(needl)) {
#pragma unroll
      for (int off = 1; off < 16; off <<= 1)
#pragma unroll
        for (int r = 0; r < 4; r++) rm[r] = fmaxf(rm[r], __shfl_xor(rm[r], off, 64));
#pragma unroll
      for (int r = 0; r < 4; r++) {
        float mn = fmaxf(mrun[r], rm[r]);
        float corr = exp2f(mrun[r] - mn);
        mrun[r] = mn;
        lrun[r] *= corr;
#pragma unroll
        for (int db = 0; db < 8; db++) accO[db][r] *= corr;
      }
    }

    // P = exp2(pm - mrun); per-lane partial row-sum
    __bf16 pbh[4][4];
#pragma unroll
    for (int kc = 0; kc < 4; kc++)
#pragma unroll
      for (int r = 0; r < 4; r++) {
        float p = exp2f(pm[kc][r] - mrun[r]);
        lrun[r] += p;
        pbh[kc][r] = (__bf16)p;
      }

    // P -> LDS (wave-private [16][64], 8-elem-chunk XOR (row&7))
    unsigned short* Pw = &Ps[w][0];
#pragma unroll
    for (int kc = 0; kc < 4; kc++)
#pragma unroll
      for (int r = 0; r < 4; r++) {
        int prow = lg * 4 + r;
        ((__bf16*)Pw)[(prow * 64 + kc * 16 + l15) ^ ((prow & 7) << 3)] = pbh[kc][r];
      }
    asm volatile("s_waitcnt lgkmcnt(0)" ::: "memory");

    // O += P * V (two K=32 slices)
    __builtin_amdgcn_s_setprio(1);
#pragma unroll
    for (int ks = 0; ks < 2; ks++) {
      bf16x8 pa = *(const bf16x8*)(Pw + ((l15 * 64 + ks * 32 + lg * 8) ^ ((l15 & 7) << 3)));
#pragma unroll
      for (int db = 0; db < 8; db++) {
        int vrow = db * 16 + l15;
        bf16x8 b = *(const bf16x8*)(Vs + vrow * 64 + (((ks * 4 + lg) ^ (l15 & 7)) * 8));
        accO[db] = mfma_bf16(pa, b, accO[db]);
      }
    }
    __builtin_amdgcn_s_setprio(0);
  }

  // epilogue: reduce per-lane partial row-sums, write
#pragma unroll
  for (int off = 1; off < 16; off <<= 1)
#pragma unroll
    for (int r = 0; r < 4; r++) lrun[r] += __shfl_xor(lrun[r], off, 64);
#pragma unroll
  for (int db = 0; db < 8; db++)
#pragma unroll
    for (int r = 0; r < 4; r++) {
      int qr = q0 + w * 16 + lg * 4 + r;
      int col = h * HDIM + db * 16 + l15;
      ((__bf16*)ab)[(long long)qr * (NQH * HDIM) + col] = (__bf16)(accO[db][r] / lrun[r]);
    }
}

// ---------------------------------------------------------------- launch
extern "C" void kernel_launch(void* const* d_in, const int* in_sizes, int n_in,
                              void* d_out, int out_size, void* d_ws, size_t ws_size,
                              hipStream_t stream) {
  const int*   positions = (const int*)d_in[0];
  const float* hs = (const float*)d_in[1];
  const float* wq = (const float*)d_in[2];
  const float* wk = (const float*)d_in[3];
  const float* wv = (const float*)d_in[4];
  const float* wo = (const float*)d_in[5];
  float* out = (float*)d_out;

  // workspace: wt 33.6 + hb/ab 16.8 + qb 16.8 + kb 4.2 + vt 4.2 = 75.5 MB
  const size_t SZ_WT = (size_t)HID * HID * 2;
  const size_t SZ_HB = (size_t)T_SEQ * HID * 2;
  const size_t SZ_QB = (size_t)T_SEQ * NQH * HDIM * 2;
  const size_t SZ_KB = (size_t)T_SEQ * NKVH * HDIM * 2;
  const size_t need = SZ_WT + SZ_HB + SZ_QB + SZ_KB * 2;
  if (ws_size < need) return;  // absmax 4.625 signature

  char* p = (char*)d_ws;
  unsigned short* wt  = (unsigned short*)p; p += SZ_WT;
  unsigned short* hb  = (unsigned short*)p; p += SZ_HB;
  unsigned short* qb  = (unsigned short*)p; p += SZ_QB;
  unsigned short* kb  = (unsigned short*)p; p += SZ_KB;
  unsigned short* vtb = (unsigned short*)p; p += SZ_KB;
  unsigned short* ab  = hb;  // alias: hb dead after KV-GEMM

  conv_f32_bf16<<<(T_SEQ * HID) / 1024, 256, 0, stream>>>(hs, hb);

  // Q projection
  transpose_conv<<<dim3((NQH * HDIM) / 32, HID / 32), 256, 0, stream>>>(wq, wt, HID, NQH * HDIM);
  gemm_bt<0><<<dim3((NQH * HDIM) / 128, T_SEQ / 128), 256, 0, stream>>>(hb, wt, qb, T_SEQ, NQH * HDIM, HID);

  // K + V projection fused (N = 2048), BM=64
  transpose_conv_kv<<<dim3((NKVH * HDIM) / 32, HID / 32, 2), 256, 0, stream>>>(wk, wv, wt);
  gemm_kv64<<<dim3(16, 32), 256, 0, stream>>>(hb, wt, kb, vtb);

  rope_all<<<(T_SEQ * (NQH + NKVH)) / 4, 256, 0, stream>>>(qb, kb, positions);

  attn_kernel<<<dim3(32, 32), 256, 0, stream>>>(qb, kb, vtb, ab);

  // output projection
  transpose_conv<<<dim3(HID / 32, (NQH * HDIM) / 32), 256, 0, stream>>>(wo, wt, NQH * HDIM, HID);
  gemm_bt<2><<<dim3(HID / 128, T_SEQ / 128), 256, 0, stream>>>(ab, wt, out, T_SEQ, HID, NQH * HDIM);
}

// Round 11
// 404.853 us; speedup vs baseline: 17.3044x; 1.1245x over previous
//
#include <hip/hip_runtime.h>

#define T_SEQ  2048
#define HID    4096
#define NQH    32
#define NKVH   8
#define HDIM   128

typedef float  f32x4  __attribute__((ext_vector_type(4)));
typedef __bf16 bf16x8 __attribute__((ext_vector_type(8)));

__device__ __forceinline__ float bf2f(unsigned short u) {
  union { unsigned int i; float f; } v; v.i = ((unsigned int)u) << 16; return v.f;
}
__device__ __forceinline__ unsigned short f2bf(float f) {
  union { float f; unsigned int i; } v; v.f = f;
  unsigned int r = v.i + 0x7fffu + ((v.i >> 16) & 1u);
  return (unsigned short)(r >> 16);
}

__device__ __forceinline__ f32x4 mfma_bf16(bf16x8 a, bf16x8 b, f32x4 c) {
  return __builtin_amdgcn_mfma_f32_16x16x32_bf16(a, b, c, 0, 0, 0);
}

#define GLOAD16(g, l)                                              \
  __builtin_amdgcn_global_load_lds(                                \
      (const __attribute__((address_space(1))) void*)(g),          \
      (__attribute__((address_space(3))) void*)(l), 16, 0, 0)

// ---------------------------------------------------------------- convert
__global__ void conv_f32_bf16(const float* __restrict__ in,
                              unsigned short* __restrict__ out) {
  long long i = ((long long)blockIdx.x * 256 + threadIdx.x) * 4;
  float4 v = *(const float4*)(in + i);
  union { unsigned short u[4]; uint2 p; } o;
  o.u[0] = f2bf(v.x); o.u[1] = f2bf(v.y); o.u[2] = f2bf(v.z); o.u[3] = f2bf(v.w);
  *(uint2*)(out + i) = o.p;
}

// ---------------------------------------------------------------- transpose v2: 64x64 tile, vectorized
// W[K][N] fp32 -> Wt[N][K] bf16
__global__ void transpose_conv(const float* __restrict__ W,
                               unsigned short* __restrict__ Wt, int K, int N) {
  __shared__ float tile[64][65];  // [n][k]
  int n0 = blockIdx.x * 64, k0 = blockIdx.y * 64;
  int tx = threadIdx.x & 15, ty = threadIdx.x >> 4;  // 16 x 16
#pragma unroll
  for (int i = 0; i < 4; i++) {
    int k = ty + 16 * i;
    float4 f = *(const float4*)(W + (long long)(k0 + k) * N + n0 + tx * 4);
    tile[tx * 4 + 0][k] = f.x;
    tile[tx * 4 + 1][k] = f.y;
    tile[tx * 4 + 2][k] = f.z;
    tile[tx * 4 + 3][k] = f.w;
  }
  __syncthreads();
#pragma unroll
  for (int i = 0; i < 4; i++) {
    int n = ty + 16 * i;
    union { unsigned short u[4]; uint2 p; } o;
    o.u[0] = f2bf(tile[n][tx * 4 + 0]);
    o.u[1] = f2bf(tile[n][tx * 4 + 1]);
    o.u[2] = f2bf(tile[n][tx * 4 + 2]);
    o.u[3] = f2bf(tile[n][tx * 4 + 3]);
    *(uint2*)(Wt + (long long)(n0 + n) * K + k0 + tx * 4) = o.p;
  }
}

// fused wk+wv transpose (z = 0 -> wk, z = 1 -> wv); dst contiguous halves of wt
__global__ void transpose_conv_kv(const float* __restrict__ Wk,
                                  const float* __restrict__ Wv,
                                  unsigned short* __restrict__ Wt) {
  __shared__ float tile[64][65];
  const int N = NKVH * HDIM, K = HID;
  const float* W = blockIdx.z ? Wv : Wk;
  unsigned short* dst = Wt + (size_t)blockIdx.z * N * K;
  int n0 = blockIdx.x * 64, k0 = blockIdx.y * 64;
  int tx = threadIdx.x & 15, ty = threadIdx.x >> 4;
#pragma unroll
  for (int i = 0; i < 4; i++) {
    int k = ty + 16 * i;
    float4 f = *(const float4*)(W + (long long)(k0 + k) * N + n0 + tx * 4);
    tile[tx * 4 + 0][k] = f.x;
    tile[tx * 4 + 1][k] = f.y;
    tile[tx * 4 + 2][k] = f.z;
    tile[tx * 4 + 3][k] = f.w;
  }
  __syncthreads();
#pragma unroll
  for (int i = 0; i < 4; i++) {
    int n = ty + 16 * i;
    union { unsigned short u[4]; uint2 p; } o;
    o.u[0] = f2bf(tile[n][tx * 4 + 0]);
    o.u[1] = f2bf(tile[n][tx * 4 + 1]);
    o.u[2] = f2bf(tile[n][tx * 4 + 2]);
    o.u[3] = f2bf(tile[n][tx * 4 + 3]);
    *(uint2*)(dst + (long long)(n0 + n) * K + k0 + tx * 4) = o.p;
  }
}

// ---------------------------------------------------------------- GEMM v2: BK=64 + LDS XOR swizzle + XCD swizzle
// C[M,N] = A[M,K](bf16,row-major) * Bt[N,K](bf16,row-major)^T
// LDS tiles [128][64] bf16; 8-chunk rows, chunk p holds global chunk p^(row&7)
// (pre-swizzled global source on staging, same XOR on ds_read side).
// EPI: 0 = bf16 row-major out; 2 = fp32 row-major out
template <int EPI>
__global__ __launch_bounds__(256) void gemm_bt(const unsigned short* __restrict__ A,
                                               const unsigned short* __restrict__ Bt,
                                               void* __restrict__ Cv,
                                               int M, int N, int K) {
  __shared__ unsigned short As[128 * 64];
  __shared__ unsigned short Bs[128 * 64];
  const int lin = blockIdx.y * gridDim.x + blockIdx.x;
  const int cpx = (gridDim.x * gridDim.y) >> 3;
  const int swz = (lin & 7) * cpx + (lin >> 3);
  const int bx = swz % gridDim.x, by = swz / gridDim.x;

  const int t = threadIdx.x;
  const int lane = t & 63, w = t >> 6;
  const int wr = w >> 1, wc = w & 1;
  const int l15 = lane & 15, lg = lane >> 4;
  const int m0 = by * 128, n0 = bx * 128;

  f32x4 acc[4][4];
#pragma unroll
  for (int i = 0; i < 4; i++)
#pragma unroll
    for (int j = 0; j < 4; j++) acc[i][j] = (f32x4){0.f, 0.f, 0.f, 0.f};

  for (int kt = 0; kt < K; kt += 64) {
    __syncthreads();
#pragma unroll
    for (int s = 0; s < 4; s++) {
      int c = t + s * 256;             // 0..1023
      int row = c >> 3, sub = c & 7;   // row 0..127, 8 chunks x 16B per row
      GLOAD16(A + (long long)(m0 + row) * K + kt + ((sub ^ (row & 7)) * 8),
              (char*)As + (w * 64 + s * 256) * 16);
      GLOAD16(Bt + (long long)(n0 + row) * K + kt + ((sub ^ (row & 7)) * 8),
              (char*)Bs + (w * 64 + s * 256) * 16);
    }
    __syncthreads();

#pragma unroll
    for (int kk = 0; kk < 2; kk++) {
      bf16x8 af[4], bfr[4];
#pragma unroll
      for (int mi = 0; mi < 4; mi++) {
        int row = wr * 64 + mi * 16 + l15;
        af[mi] = *(const bf16x8*)(As + row * 64 + (((kk * 4 + lg) ^ (row & 7)) * 8));
      }
#pragma unroll
      for (int ni = 0; ni < 4; ni++) {
        int row = wc * 64 + ni * 16 + l15;
        bfr[ni] = *(const bf16x8*)(Bs + row * 64 + (((kk * 4 + lg) ^ (row & 7)) * 8));
      }
#pragma unroll
      for (int mi = 0; mi < 4; mi++)
#pragma unroll
        for (int ni = 0; ni < 4; ni++)
          acc[mi][ni] = mfma_bf16(af[mi], bfr[ni], acc[mi][ni]);
    }
  }

  const int row0 = m0 + wr * 64, col0 = n0 + wc * 64;
#pragma unroll
  for (int mi = 0; mi < 4; mi++)
#pragma unroll
    for (int ni = 0; ni < 4; ni++) {
      int rbase = row0 + mi * 16 + lg * 4;
      int col = col0 + ni * 16 + l15;
#pragma unroll
      for (int r = 0; r < 4; r++) {
        float v = acc[mi][ni][r];
        if (EPI == 0)
          ((unsigned short*)Cv)[(long long)(rbase + r) * N + col] = f2bf(v);
        else
          ((float*)Cv)[(long long)(rbase + r) * N + col] = v;
      }
    }
}

// ---------------------------------------------------------------- KV GEMM, BM=64 (512 blocks -> 2/CU)
// cols<1024 -> kb [2048][1024]; cols>=1024 -> vtb [1024][2048] via LDS-transpose epilogue
__global__ __launch_bounds__(256) void gemm_kv64(const unsigned short* __restrict__ A,
                                                 const unsigned short* __restrict__ Bt,
                                                 unsigned short* __restrict__ Ckv,
                                                 unsigned short* __restrict__ Cvt) {
  __shared__ unsigned short As[64 * 32];
  __shared__ unsigned short Bs[128 * 32];
  __shared__ unsigned short Tt[128 * 64];  // V transpose bounce
  const int lin = blockIdx.y * gridDim.x + blockIdx.x;  // grid (16,32) = 512
  const int swz = (lin & 7) * 64 + (lin >> 3);
  const int bx = swz & 15, by = swz >> 4;

  const int t = threadIdx.x;
  const int lane = t & 63, w = t >> 6;
  const int wr = w >> 1, wc = w & 1;
  const int l15 = lane & 15, lg = lane >> 4;
  const int m0 = by * 64, n0 = bx * 128;
  const int K = HID;

  f32x4 acc[2][4];
#pragma unroll
  for (int i = 0; i < 2; i++)
#pragma unroll
    for (int j = 0; j < 4; j++) acc[i][j] = (f32x4){0.f, 0.f, 0.f, 0.f};

  const int c0 = t, c1 = t + 256;

  for (int kt = 0; kt < K; kt += 32) {
    __syncthreads();
    GLOAD16(A + (long long)(m0 + (c0 >> 2)) * K + kt + (c0 & 3) * 8,
            (char*)As + (w * 64) * 16);
    GLOAD16(Bt + (long long)(n0 + (c0 >> 2)) * K + kt + (c0 & 3) * 8,
            (char*)Bs + (w * 64) * 16);
    GLOAD16(Bt + (long long)(n0 + (c1 >> 2)) * K + kt + (c1 & 3) * 8,
            (char*)Bs + (w * 64 + 256) * 16);
    __syncthreads();

    bf16x8 af[2], bfr[4];
#pragma unroll
    for (int mi = 0; mi < 2; mi++)
      af[mi] = *(const bf16x8*)(As + (wr * 32 + mi * 16 + l15) * 32 + lg * 8);
#pragma unroll
    for (int ni = 0; ni < 4; ni++)
      bfr[ni] = *(const bf16x8*)(Bs + (wc * 64 + ni * 16 + l15) * 32 + lg * 8);
#pragma unroll
    for (int mi = 0; mi < 2; mi++)
#pragma unroll
      for (int ni = 0; ni < 4; ni++)
        acc[mi][ni] = mfma_bf16(af[mi], bfr[ni], acc[mi][ni]);
  }

  const int row0 = m0 + wr * 32, col0 = n0 + wc * 64;
  if (n0 < 1024) {
#pragma unroll
    for (int mi = 0; mi < 2; mi++)
#pragma unroll
      for (int ni = 0; ni < 4; ni++) {
        int rbase = row0 + mi * 16 + lg * 4;
        int col = col0 + ni * 16 + l15;
#pragma unroll
        for (int r = 0; r < 4; r++)
          Ckv[(long long)(rbase + r) * 1024 + col] = f2bf(acc[mi][ni][r]);
      }
  } else {
#pragma unroll
    for (int mi = 0; mi < 2; mi++)
#pragma unroll
      for (int ni = 0; ni < 4; ni++) {
        int nloc = wc * 64 + ni * 16 + l15;
#pragma unroll
        for (int r = 0; r < 4; r++) {
          int mloc = wr * 32 + mi * 16 + lg * 4 + r;
          Tt[nloc * 64 + (mloc ^ ((nloc & 7) << 3))] = f2bf(acc[mi][ni][r]);
        }
      }
    __syncthreads();
    const int nloc = t >> 1;
#pragma unroll
    for (int cc = 0; cc < 4; cc++) {
      int ci = (t & 1) * 4 + cc;
      int sc = ci ^ (nloc & 7);
      uint4 v = *(const uint4*)(Tt + nloc * 64 + sc * 8);
      *(uint4*)(Cvt + (long long)(n0 - 1024 + nloc) * T_SEQ + m0 + ci * 8) = v;
    }
  }
}

// ---------------------------------------------------------------- RoPE (neox, fp64 angles), fused q+k
// Q rows additionally pre-scaled by 1/sqrt(128)*log2(e) (softmax scale folded in)
__global__ void rope_all(unsigned short* __restrict__ qb,
                         unsigned short* __restrict__ kb,
                         const int* __restrict__ positions) {
  const int w = threadIdx.x >> 6, d = threadIdx.x & 63;
  const int gid = blockIdx.x * 4 + w;
  unsigned short* row;
  int t;
  bool isq;
  if (gid < T_SEQ * NQH) {
    int h = gid & (NQH - 1); t = gid >> 5;
    row = qb + (size_t)t * (NQH * HDIM) + (size_t)h * HDIM;
    isq = true;
  } else {
    int g = gid - T_SEQ * NQH;
    int h = g & (NKVH - 1); t = g >> 3;
    row = kb + (size_t)t * (NKVH * HDIM) + (size_t)h * HDIM;
    isq = false;
  }
  double inv = exp2(-(double)d * 0.20762050593046014);  // 10000^(-d/64)
  double ang = (double)positions[t] * inv;
  double c = cos(ang), s = sin(ang);
  if (isq) { c *= 0.12751744416986895; s *= 0.12751744416986895; }
  float x1 = bf2f(row[d]), x2 = bf2f(row[d + 64]);
  row[d]      = f2bf((float)((double)x1 * c - (double)x2 * s));
  row[d + 64] = f2bf((float)((double)x2 * c + (double)x1 * s));
}

// ---------------------------------------------------------------- flash attention v6 (unchanged)
__global__ __launch_bounds__(256) void attn_kernel(const unsigned short* __restrict__ qb,
                                                   const unsigned short* __restrict__ kb,
                                                   const unsigned short* __restrict__ vt,
                                                   unsigned short* __restrict__ ab) {
  __shared__ unsigned short Ks[64 * 128];
  __shared__ unsigned short Vs[128 * 64];
  __shared__ unsigned short Ps[4][16 * 64];

  const int lin = blockIdx.y * gridDim.x + blockIdx.x;  // 0..1023
  const int swz = (lin & 7) * 128 + (lin >> 3);
  const int bx = swz & 31;
  const int h  = swz >> 5;
  const int kvh = h >> 2;
  const int j  = 31 - bx;  // longest first
  const int q0 = j * 64;
  const int t = threadIdx.x, lane = t & 63, w = t >> 6;
  const int l15 = lane & 15, lg = lane >> 4;

  bf16x8 qf[4];
#pragma unroll
  for (int kk = 0; kk < 4; kk++)
    qf[kk] = *(const bf16x8*)(qb + (long long)(q0 + w * 16 + l15) * (NQH * HDIM) +
                              h * HDIM + kk * 32 + lg * 8);

  f32x4 accO[8];
#pragma unroll
  for (int db = 0; db < 8; db++) accO[db] = (f32x4){0.f, 0.f, 0.f, 0.f};
  float mrun[4] = {-3e38f, -3e38f, -3e38f, -3e38f};
  float lrun[4] = {0.f, 0.f, 0.f, 0.f};

  const int nt = j + 1;
  for (int kt = 0; kt < nt; kt++) {
    __syncthreads();
#pragma unroll
    for (int s = 0; s < 4; s++) {
      int c = t + s * 256;
      int row = c >> 4, chk = c & 15;
      GLOAD16(kb + (long long)(kt * 64 + row) * (NKVH * HDIM) + kvh * HDIM +
                  ((chk ^ (row & 7)) * 8),
              (char*)Ks + (w * 64 + s * 256) * 16);
    }
#pragma unroll
    for (int s = 0; s < 4; s++) {
      int c = t + s * 256;
      int row = c >> 3, chk = c & 7;
      GLOAD16(vt + (long long)(kvh * HDIM + row) * T_SEQ + kt * 64 +
                  ((chk ^ (row & 7)) * 8),
              (char*)Vs + (w * 64 + s * 256) * 16);
    }
    __syncthreads();

    f32x4 accS[4];
#pragma unroll
    for (int kc = 0; kc < 4; kc++) accS[kc] = (f32x4){0.f, 0.f, 0.f, 0.f};
    __builtin_amdgcn_s_setprio(1);
#pragma unroll
    for (int kk = 0; kk < 4; kk++)
#pragma unroll
      for (int kc = 0; kc < 4; kc++) {
        int row = kc * 16 + l15;
        bf16x8 b = *(const bf16x8*)(Ks + row * 128 + (((kk * 4 + lg) ^ (l15 & 7)) * 8));
        accS[kc] = mfma_bf16(qf[kk], b, accS[kc]);
      }
    __builtin_amdgcn_s_setprio(0);

    float pm[4][4];
    if (kt == j) {
#pragma unroll
      for (int kc = 0; kc < 4; kc++) {
        int kcl = kc * 16 + l15;
#pragma unroll
        for (int r = 0; r < 4; r++)
          pm[kc][r] = (kcl > w * 16 + lg * 4 + r) ? -3e38f : accS[kc][r];
      }
    } else {
#pragma unroll
      for (int kc = 0; kc < 4; kc++)
#pragma unroll
        for (int r = 0; r < 4; r++) pm[kc][r] = accS[kc][r];
    }

    float rm[4];
#pragma unroll
    for (int r = 0; r < 4; r++)
      rm[r] = fmaxf(fmaxf(pm[0][r], pm[1][r]), fmaxf(pm[2][r], pm[3][r]));
    int needl = 0;
#pragma unroll
    for (int r = 0; r < 4; r++) needl |= (rm[r] > mrun[r] + 8.f) ? 1 : 0;
    if (__any(needl)) {
#pragma unroll
      for (int off = 1; off < 16; off <<= 1)
#pragma unroll
        for (int r = 0; r < 4; r++) rm[r] = fmaxf(rm[r], __shfl_xor(rm[r], off, 64));
#pragma unroll
      for (int r = 0; r < 4; r++) {
        float mn = fmaxf(mrun[r], rm[r]);
        float corr = exp2f(mrun[r] - mn);
        mrun[r] = mn;
        lrun[r] *= corr;
#pragma unroll
        for (int db = 0; db < 8; db++) accO[db][r] *= corr;
      }
    }

    __bf16 pbh[4][4];
#pragma unroll
    for (int kc = 0; kc < 4; kc++)
#pragma unroll
      for (int r = 0; r < 4; r++) {
        float p = exp2f(pm[kc][r] - mrun[r]);
        lrun[r] += p;
        pbh[kc][r] = (__bf16)p;
      }

    unsigned short* Pw = &Ps[w][0];
#pragma unroll
    for (int kc = 0; kc < 4; kc++)
#pragma unroll
      for (int r = 0; r < 4; r++) {
        int prow = lg * 4 + r;
        ((__bf16*)Pw)[(prow * 64 + kc * 16 + l15) ^ ((prow & 7) << 3)] = pbh[kc][r];
      }
    asm volatile("s_waitcnt lgkmcnt(0)" ::: "memory");

    __builtin_amdgcn_s_setprio(1);
#pragma unroll
    for (int ks = 0; ks < 2; ks++) {
      bf16x8 pa = *(const bf16x8*)(Pw + ((l15 * 64 + ks * 32 + lg * 8) ^ ((l15 & 7) << 3)));
#pragma unroll
      for (int db = 0; db < 8; db++) {
        int vrow = db * 16 + l15;
        bf16x8 b = *(const bf16x8*)(Vs + vrow * 64 + (((ks * 4 + lg) ^ (l15 & 7)) * 8));
        accO[db] = mfma_bf16(pa, b, accO[db]);
      }
    }
    __builtin_amdgcn_s_setprio(0);
  }

#pragma unroll
  for (int off = 1; off < 16; off <<= 1)
#pragma unroll
    for (int r = 0; r < 4; r++) lrun[r] += __shfl_xor(lrun[r], off, 64);
#pragma unroll
  for (int db = 0; db < 8; db++)
#pragma unroll
    for (int r = 0; r < 4; r++) {
      int qr = q0 + w * 16 + lg * 4 + r;
      int col = h * HDIM + db * 16 + l15;
      ((__bf16*)ab)[(long long)qr * (NQH * HDIM) + col] = (__bf16)(accO[db][r] / lrun[r]);
    }
}

// ---------------------------------------------------------------- launch
extern "C" void kernel_launch(void* const* d_in, const int* in_sizes, int n_in,
                              void* d_out, int out_size, void* d_ws, size_t ws_size,
                              hipStream_t stream) {
  const int*   positions = (const int*)d_in[0];
  const float* hs = (const float*)d_in[1];
  const float* wq = (const float*)d_in[2];
  const float* wk = (const float*)d_in[3];
  const float* wv = (const float*)d_in[4];
  const float* wo = (const float*)d_in[5];
  float* out = (float*)d_out;

  const size_t SZ_WT = (size_t)HID * HID * 2;
  const size_t SZ_HB = (size_t)T_SEQ * HID * 2;
  const size_t SZ_QB = (size_t)T_SEQ * NQH * HDIM * 2;
  const size_t SZ_KB = (size_t)T_SEQ * NKVH * HDIM * 2;
  const size_t need = SZ_WT + SZ_HB + SZ_QB + SZ_KB * 2;
  if (ws_size < need) return;  // absmax 4.625 signature

  char* p = (char*)d_ws;
  unsigned short* wt  = (unsigned short*)p; p += SZ_WT;
  unsigned short* hb  = (unsigned short*)p; p += SZ_HB;
  unsigned short* qb  = (unsigned short*)p; p += SZ_QB;
  unsigned short* kb  = (unsigned short*)p; p += SZ_KB;
  unsigned short* vtb = (unsigned short*)p; p += SZ_KB;
  unsigned short* ab  = hb;  // alias: hb dead after KV-GEMM

  conv_f32_bf16<<<(T_SEQ * HID) / 1024, 256, 0, stream>>>(hs, hb);

  // Q projection
  transpose_conv<<<dim3((NQH * HDIM) / 64, HID / 64), 256, 0, stream>>>(wq, wt, HID, NQH * HDIM);
  gemm_bt<0><<<dim3((NQH * HDIM) / 128, T_SEQ / 128), 256, 0, stream>>>(hb, wt, qb, T_SEQ, NQH * HDIM, HID);

  // K + V projection fused (N = 2048), BM=64
  transpose_conv_kv<<<dim3((NKVH * HDIM) / 64, HID / 64, 2), 256, 0, stream>>>(wk, wv, wt);
  gemm_kv64<<<dim3(16, 32), 256, 0, stream>>>(hb, wt, kb, vtb);

  rope_all<<<(T_SEQ * (NQH + NKVH)) / 4, 256, 0, stream>>>(qb, kb, positions);

  attn_kernel<<<dim3(32, 32), 256, 0, stream>>>(qb, kb, vtb, ab);

  // output projection
  transpose_conv<<<dim3(HID / 64, (NQH * HDIM) / 64), 256, 0, stream>>>(wo, wt, NQH * HDIM, HID);
  gemm_bt<2><<<dim3(HID / 128, T_SEQ / 128), 256, 0, stream>>>(ab, wt, out, T_SEQ, HID, NQH * HDIM);
}

// Round 12
// 399.888 us; speedup vs baseline: 17.5192x; 1.0124x over previous
//
#include <hip/hip_runtime.h>

#define T_SEQ  2048
#define HID    4096
#define NQH    32
#define NKVH   8
#define HDIM   128

typedef float  f32x4  __attribute__((ext_vector_type(4)));
typedef __bf16 bf16x8 __attribute__((ext_vector_type(8)));

__device__ __forceinline__ float bf2f(unsigned short u) {
  union { unsigned int i; float f; } v; v.i = ((unsigned int)u) << 16; return v.f;
}
__device__ __forceinline__ unsigned short f2bf(float f) {
  union { float f; unsigned int i; } v; v.f = f;
  unsigned int r = v.i + 0x7fffu + ((v.i >> 16) & 1u);
  return (unsigned short)(r >> 16);
}

__device__ __forceinline__ f32x4 mfma_bf16(bf16x8 a, bf16x8 b, f32x4 c) {
  return __builtin_amdgcn_mfma_f32_16x16x32_bf16(a, b, c, 0, 0, 0);
}

#define GLOAD16(g, l)                                              \
  __builtin_amdgcn_global_load_lds(                                \
      (const __attribute__((address_space(1))) void*)(g),          \
      (__attribute__((address_space(3))) void*)(l), 16, 0, 0)

// ---------------------------------------------------------------- convert
__global__ void conv_f32_bf16(const float* __restrict__ in,
                              unsigned short* __restrict__ out) {
  long long i = ((long long)blockIdx.x * 256 + threadIdx.x) * 4;
  float4 v = *(const float4*)(in + i);
  union { unsigned short u[4]; uint2 p; } o;
  o.u[0] = f2bf(v.x); o.u[1] = f2bf(v.y); o.u[2] = f2bf(v.z); o.u[3] = f2bf(v.w);
  *(uint2*)(out + i) = o.p;
}

// ---------------------------------------------------------------- transpose v2: 64x64 tile, vectorized
__global__ void transpose_conv(const float* __restrict__ W,
                               unsigned short* __restrict__ Wt, int K, int N) {
  __shared__ float tile[64][65];  // [n][k]
  int n0 = blockIdx.x * 64, k0 = blockIdx.y * 64;
  int tx = threadIdx.x & 15, ty = threadIdx.x >> 4;  // 16 x 16
#pragma unroll
  for (int i = 0; i < 4; i++) {
    int k = ty + 16 * i;
    float4 f = *(const float4*)(W + (long long)(k0 + k) * N + n0 + tx * 4);
    tile[tx * 4 + 0][k] = f.x;
    tile[tx * 4 + 1][k] = f.y;
    tile[tx * 4 + 2][k] = f.z;
    tile[tx * 4 + 3][k] = f.w;
  }
  __syncthreads();
#pragma unroll
  for (int i = 0; i < 4; i++) {
    int n = ty + 16 * i;
    union { unsigned short u[4]; uint2 p; } o;
    o.u[0] = f2bf(tile[n][tx * 4 + 0]);
    o.u[1] = f2bf(tile[n][tx * 4 + 1]);
    o.u[2] = f2bf(tile[n][tx * 4 + 2]);
    o.u[3] = f2bf(tile[n][tx * 4 + 3]);
    *(uint2*)(Wt + (long long)(n0 + n) * K + k0 + tx * 4) = o.p;
  }
}

// fused wk+wv transpose (z = 0 -> wk, z = 1 -> wv); dst contiguous halves of wt
__global__ void transpose_conv_kv(const float* __restrict__ Wk,
                                  const float* __restrict__ Wv,
                                  unsigned short* __restrict__ Wt) {
  __shared__ float tile[64][65];
  const int N = NKVH * HDIM, K = HID;
  const float* W = blockIdx.z ? Wv : Wk;
  unsigned short* dst = Wt + (size_t)blockIdx.z * N * K;
  int n0 = blockIdx.x * 64, k0 = blockIdx.y * 64;
  int tx = threadIdx.x & 15, ty = threadIdx.x >> 4;
#pragma unroll
  for (int i = 0; i < 4; i++) {
    int k = ty + 16 * i;
    float4 f = *(const float4*)(W + (long long)(k0 + k) * N + n0 + tx * 4);
    tile[tx * 4 + 0][k] = f.x;
    tile[tx * 4 + 1][k] = f.y;
    tile[tx * 4 + 2][k] = f.z;
    tile[tx * 4 + 3][k] = f.w;
  }
  __syncthreads();
#pragma unroll
  for (int i = 0; i < 4; i++) {
    int n = ty + 16 * i;
    union { unsigned short u[4]; uint2 p; } o;
    o.u[0] = f2bf(tile[n][tx * 4 + 0]);
    o.u[1] = f2bf(tile[n][tx * 4 + 1]);
    o.u[2] = f2bf(tile[n][tx * 4 + 2]);
    o.u[3] = f2bf(tile[n][tx * 4 + 3]);
    *(uint2*)(dst + (long long)(n0 + n) * K + k0 + tx * 4) = o.p;
  }
}

// ---------------------------------------------------------------- GEMM v2: BK=64 + LDS XOR swizzle + XCD swizzle
// EPI: 0 = bf16 row-major out; 2 = fp32 row-major out
template <int EPI>
__global__ __launch_bounds__(256) void gemm_bt(const unsigned short* __restrict__ A,
                                               const unsigned short* __restrict__ Bt,
                                               void* __restrict__ Cv,
                                               int M, int N, int K) {
  __shared__ unsigned short As[128 * 64];
  __shared__ unsigned short Bs[128 * 64];
  const int lin = blockIdx.y * gridDim.x + blockIdx.x;
  const int cpx = (gridDim.x * gridDim.y) >> 3;
  const int swz = (lin & 7) * cpx + (lin >> 3);
  const int bx = swz % gridDim.x, by = swz / gridDim.x;

  const int t = threadIdx.x;
  const int lane = t & 63, w = t >> 6;
  const int wr = w >> 1, wc = w & 1;
  const int l15 = lane & 15, lg = lane >> 4;
  const int m0 = by * 128, n0 = bx * 128;

  f32x4 acc[4][4];
#pragma unroll
  for (int i = 0; i < 4; i++)
#pragma unroll
    for (int j = 0; j < 4; j++) acc[i][j] = (f32x4){0.f, 0.f, 0.f, 0.f};

  for (int kt = 0; kt < K; kt += 64) {
    __syncthreads();
#pragma unroll
    for (int s = 0; s < 4; s++) {
      int c = t + s * 256;             // 0..1023
      int row = c >> 3, sub = c & 7;   // row 0..127, 8 chunks x 16B per row
      GLOAD16(A + (long long)(m0 + row) * K + kt + ((sub ^ (row & 7)) * 8),
              (char*)As + (w * 64 + s * 256) * 16);
      GLOAD16(Bt + (long long)(n0 + row) * K + kt + ((sub ^ (row & 7)) * 8),
              (char*)Bs + (w * 64 + s * 256) * 16);
    }
    __syncthreads();

#pragma unroll
    for (int kk = 0; kk < 2; kk++) {
      bf16x8 af[4], bfr[4];
#pragma unroll
      for (int mi = 0; mi < 4; mi++) {
        int row = wr * 64 + mi * 16 + l15;
        af[mi] = *(const bf16x8*)(As + row * 64 + (((kk * 4 + lg) ^ (row & 7)) * 8));
      }
#pragma unroll
      for (int ni = 0; ni < 4; ni++) {
        int row = wc * 64 + ni * 16 + l15;
        bfr[ni] = *(const bf16x8*)(Bs + row * 64 + (((kk * 4 + lg) ^ (row & 7)) * 8));
      }
#pragma unroll
      for (int mi = 0; mi < 4; mi++)
#pragma unroll
        for (int ni = 0; ni < 4; ni++)
          acc[mi][ni] = mfma_bf16(af[mi], bfr[ni], acc[mi][ni]);
    }
  }

  const int row0 = m0 + wr * 64, col0 = n0 + wc * 64;
#pragma unroll
  for (int mi = 0; mi < 4; mi++)
#pragma unroll
    for (int ni = 0; ni < 4; ni++) {
      int rbase = row0 + mi * 16 + lg * 4;
      int col = col0 + ni * 16 + l15;
#pragma unroll
      for (int r = 0; r < 4; r++) {
        float v = acc[mi][ni][r];
        if (EPI == 0)
          ((unsigned short*)Cv)[(long long)(rbase + r) * N + col] = f2bf(v);
        else
          ((float*)Cv)[(long long)(rbase + r) * N + col] = v;
      }
    }
}

// ---------------------------------------------------------------- KV GEMM v2: BM=64, BK=64 + XOR swizzle
// cols<1024 -> kb [2048][1024]; cols>=1024 -> vtb [1024][2048] via LDS-transpose epilogue
__global__ __launch_bounds__(256) void gemm_kv64(const unsigned short* __restrict__ A,
                                                 const unsigned short* __restrict__ Bt,
                                                 unsigned short* __restrict__ Ckv,
                                                 unsigned short* __restrict__ Cvt) {
  __shared__ unsigned short As[64 * 64];
  __shared__ unsigned short Bs[128 * 64];
  __shared__ unsigned short Tt[128 * 64];  // V transpose bounce
  const int lin = blockIdx.y * gridDim.x + blockIdx.x;  // grid (16,32) = 512
  const int swz = (lin & 7) * 64 + (lin >> 3);
  const int bx = swz & 15, by = swz >> 4;

  const int t = threadIdx.x;
  const int lane = t & 63, w = t >> 6;
  const int wr = w >> 1, wc = w & 1;
  const int l15 = lane & 15, lg = lane >> 4;
  const int m0 = by * 64, n0 = bx * 128;
  const int K = HID;

  f32x4 acc[2][4];
#pragma unroll
  for (int i = 0; i < 2; i++)
#pragma unroll
    for (int j = 0; j < 4; j++) acc[i][j] = (f32x4){0.f, 0.f, 0.f, 0.f};

  for (int kt = 0; kt < K; kt += 64) {
    __syncthreads();
    // A: 64 rows x 8 chunks = 512
#pragma unroll
    for (int s = 0; s < 2; s++) {
      int c = t + s * 256;
      int row = c >> 3, sub = c & 7;
      GLOAD16(A + (long long)(m0 + row) * K + kt + ((sub ^ (row & 7)) * 8),
              (char*)As + (w * 64 + s * 256) * 16);
    }
    // B: 128 rows x 8 chunks = 1024
#pragma unroll
    for (int s = 0; s < 4; s++) {
      int c = t + s * 256;
      int row = c >> 3, sub = c & 7;
      GLOAD16(Bt + (long long)(n0 + row) * K + kt + ((sub ^ (row & 7)) * 8),
              (char*)Bs + (w * 64 + s * 256) * 16);
    }
    __syncthreads();

#pragma unroll
    for (int kk = 0; kk < 2; kk++) {
      bf16x8 af[2], bfr[4];
#pragma unroll
      for (int mi = 0; mi < 2; mi++) {
        int row = wr * 32 + mi * 16 + l15;
        af[mi] = *(const bf16x8*)(As + row * 64 + (((kk * 4 + lg) ^ (row & 7)) * 8));
      }
#pragma unroll
      for (int ni = 0; ni < 4; ni++) {
        int row = wc * 64 + ni * 16 + l15;
        bfr[ni] = *(const bf16x8*)(Bs + row * 64 + (((kk * 4 + lg) ^ (row & 7)) * 8));
      }
#pragma unroll
      for (int mi = 0; mi < 2; mi++)
#pragma unroll
        for (int ni = 0; ni < 4; ni++)
          acc[mi][ni] = mfma_bf16(af[mi], bfr[ni], acc[mi][ni]);
    }
  }

  const int row0 = m0 + wr * 32, col0 = n0 + wc * 64;
  if (n0 < 1024) {
#pragma unroll
    for (int mi = 0; mi < 2; mi++)
#pragma unroll
      for (int ni = 0; ni < 4; ni++) {
        int rbase = row0 + mi * 16 + lg * 4;
        int col = col0 + ni * 16 + l15;
#pragma unroll
        for (int r = 0; r < 4; r++)
          Ckv[(long long)(rbase + r) * 1024 + col] = f2bf(acc[mi][ni][r]);
      }
  } else {
#pragma unroll
    for (int mi = 0; mi < 2; mi++)
#pragma unroll
      for (int ni = 0; ni < 4; ni++) {
        int nloc = wc * 64 + ni * 16 + l15;
#pragma unroll
        for (int r = 0; r < 4; r++) {
          int mloc = wr * 32 + mi * 16 + lg * 4 + r;
          Tt[nloc * 64 + (mloc ^ ((nloc & 7) << 3))] = f2bf(acc[mi][ni][r]);
        }
      }
    __syncthreads();
    const int nloc = t >> 1;
#pragma unroll
    for (int cc = 0; cc < 4; cc++) {
      int ci = (t & 1) * 4 + cc;
      int sc = ci ^ (nloc & 7);
      uint4 v = *(const uint4*)(Tt + nloc * 64 + sc * 8);
      *(uint4*)(Cvt + (long long)(n0 - 1024 + nloc) * T_SEQ + m0 + ci * 8) = v;
    }
  }
}

// ---------------------------------------------------------------- RoPE (neox, fp64 angles), fused q+k
// Q rows additionally pre-scaled by 1/sqrt(128)*log2(e) (softmax scale folded in)
__global__ void rope_all(unsigned short* __restrict__ qb,
                         unsigned short* __restrict__ kb,
                         const int* __restrict__ positions) {
  const int w = threadIdx.x >> 6, d = threadIdx.x & 63;
  const int gid = blockIdx.x * 4 + w;
  unsigned short* row;
  int t;
  bool isq;
  if (gid < T_SEQ * NQH) {
    int h = gid & (NQH - 1); t = gid >> 5;
    row = qb + (size_t)t * (NQH * HDIM) + (size_t)h * HDIM;
    isq = true;
  } else {
    int g = gid - T_SEQ * NQH;
    int h = g & (NKVH - 1); t = g >> 3;
    row = kb + (size_t)t * (NKVH * HDIM) + (size_t)h * HDIM;
    isq = false;
  }
  double inv = exp2(-(double)d * 0.20762050593046014);  // 10000^(-d/64)
  double ang = (double)positions[t] * inv;
  double c = cos(ang), s = sin(ang);
  if (isq) { c *= 0.12751744416986895; s *= 0.12751744416986895; }
  float x1 = bf2f(row[d]), x2 = bf2f(row[d + 64]);
  row[d]      = f2bf((float)((double)x1 * c - (double)x2 * s));
  row[d + 64] = f2bf((float)((double)x2 * c + (double)x1 * s));
}

// ---------------------------------------------------------------- flash attention v7
// grid (32,32); block = 4 waves x 16 q-rows = one 64-row q-tile; KVBLK=64 single-buffered.
// Zigzag q-tile assignment: j = (h&1) ? bx : 31-bx  -> per-CU work balanced
// (fixes the adversarial mapping where CU c got j=31-c for all 4 resident blocks).
__global__ __launch_bounds__(256) void attn_kernel(const unsigned short* __restrict__ qb,
                                                   const unsigned short* __restrict__ kb,
                                                   const unsigned short* __restrict__ vt,
                                                   unsigned short* __restrict__ ab) {
  __shared__ unsigned short Ks[64 * 128];
  __shared__ unsigned short Vs[128 * 64];
  __shared__ unsigned short Ps[4][16 * 64];

  const int lin = blockIdx.y * gridDim.x + blockIdx.x;  // 0..1023
  const int swz = (lin & 7) * 128 + (lin >> 3);
  const int bx = swz & 31;
  const int h  = swz >> 5;
  const int kvh = h >> 2;
  const int j  = (h & 1) ? bx : 31 - bx;  // zigzag balance
  const int q0 = j * 64;
  const int t = threadIdx.x, lane = t & 63, w = t >> 6;
  const int l15 = lane & 15, lg = lane >> 4;

  bf16x8 qf[4];
#pragma unroll
  for (int kk = 0; kk < 4; kk++)
    qf[kk] = *(const bf16x8*)(qb + (long long)(q0 + w * 16 + l15) * (NQH * HDIM) +
                              h * HDIM + kk * 32 + lg * 8);

  f32x4 accO[8];
#pragma unroll
  for (int db = 0; db < 8; db++) accO[db] = (f32x4){0.f, 0.f, 0.f, 0.f};
  float mrun[4] = {-3e38f, -3e38f, -3e38f, -3e38f};
  float lrun[4] = {0.f, 0.f, 0.f, 0.f};

  const int nt = j + 1;
  for (int kt = 0; kt < nt; kt++) {
    __syncthreads();
#pragma unroll
    for (int s = 0; s < 4; s++) {
      int c = t + s * 256;
      int row = c >> 4, chk = c & 15;
      GLOAD16(kb + (long long)(kt * 64 + row) * (NKVH * HDIM) + kvh * HDIM +
                  ((chk ^ (row & 7)) * 8),
              (char*)Ks + (w * 64 + s * 256) * 16);
    }
#pragma unroll
    for (int s = 0; s < 4; s++) {
      int c = t + s * 256;
      int row = c >> 3, chk = c & 7;
      GLOAD16(vt + (long long)(kvh * HDIM + row) * T_SEQ + kt * 64 +
                  ((chk ^ (row & 7)) * 8),
              (char*)Vs + (w * 64 + s * 256) * 16);
    }
    __syncthreads();

    f32x4 accS[4];
#pragma unroll
    for (int kc = 0; kc < 4; kc++) accS[kc] = (f32x4){0.f, 0.f, 0.f, 0.f};
    __builtin_amdgcn_s_setprio(1);
#pragma unroll
    for (int kk = 0; kk < 4; kk++)
#pragma unroll
      for (int kc = 0; kc < 4; kc++) {
        int row = kc * 16 + l15;
        bf16x8 b = *(const bf16x8*)(Ks + row * 128 + (((kk * 4 + lg) ^ (l15 & 7)) * 8));
        accS[kc] = mfma_bf16(qf[kk], b, accS[kc]);
      }
    __builtin_amdgcn_s_setprio(0);

    float pm[4][4];
    if (kt == j) {
#pragma unroll
      for (int kc = 0; kc < 4; kc++) {
        int kcl = kc * 16 + l15;
#pragma unroll
        for (int r = 0; r < 4; r++)
          pm[kc][r] = (kcl > w * 16 + lg * 4 + r) ? -3e38f : accS[kc][r];
      }
    } else {
#pragma unroll
      for (int kc = 0; kc < 4; kc++)
#pragma unroll
        for (int r = 0; r < 4; r++) pm[kc][r] = accS[kc][r];
    }

    float rm[4];
#pragma unroll
    for (int r = 0; r < 4; r++)
      rm[r] = fmaxf(fmaxf(pm[0][r], pm[1][r]), fmaxf(pm[2][r], pm[3][r]));
    int needl = 0;
#pragma unroll
    for (int r = 0; r < 4; r++) needl |= (rm[r] > mrun[r] + 8.f) ? 1 : 0;
    if (__any(needl)) {
#pragma unroll
      for (int off = 1; off < 16; off <<= 1)
#pragma unroll
        for (int r = 0; r < 4; r++) rm[r] = fmaxf(rm[r], __shfl_xor(rm[r], off, 64));
#pragma unroll
      for (int r = 0; r < 4; r++) {
        float mn = fmaxf(mrun[r], rm[r]);
        float corr = exp2f(mrun[r] - mn);
        mrun[r] = mn;
        lrun[r] *= corr;
#pragma unroll
        for (int db = 0; db < 8; db++) accO[db][r] *= corr;
      }
    }

    __bf16 pbh[4][4];
#pragma unroll
    for (int kc = 0; kc < 4; kc++)
#pragma unroll
      for (int r = 0; r < 4; r++) {
        float p = exp2f(pm[kc][r] - mrun[r]);
        lrun[r] += p;
        pbh[kc][r] = (__bf16)p;
      }

    unsigned short* Pw = &Ps[w][0];
#pragma unroll
    for (int kc = 0; kc < 4; kc++)
#pragma unroll
      for (int r = 0; r < 4; r++) {
        int prow = lg * 4 + r;
        ((__bf16*)Pw)[(prow * 64 + kc * 16 + l15) ^ ((prow & 7) << 3)] = pbh[kc][r];
      }
    asm volatile("s_waitcnt lgkmcnt(0)" ::: "memory");

    __builtin_amdgcn_s_setprio(1);
#pragma unroll
    for (int ks = 0; ks < 2; ks++) {
      bf16x8 pa = *(const bf16x8*)(Pw + ((l15 * 64 + ks * 32 + lg * 8) ^ ((l15 & 7) << 3)));
#pragma unroll
      for (int db = 0; db < 8; db++) {
        int vrow = db * 16 + l15;
        bf16x8 b = *(const bf16x8*)(Vs + vrow * 64 + (((ks * 4 + lg) ^ (l15 & 7)) * 8));
        accO[db] = mfma_bf16(pa, b, accO[db]);
      }
    }
    __builtin_amdgcn_s_setprio(0);
  }

#pragma unroll
  for (int off = 1; off < 16; off <<= 1)
#pragma unroll
    for (int r = 0; r < 4; r++) lrun[r] += __shfl_xor(lrun[r], off, 64);
#pragma unroll
  for (int db = 0; db < 8; db++)
#pragma unroll
    for (int r = 0; r < 4; r++) {
      int qr = q0 + w * 16 + lg * 4 + r;
      int col = h * HDIM + db * 16 + l15;
      ((__bf16*)ab)[(long long)qr * (NQH * HDIM) + col] = (__bf16)(accO[db][r] / lrun[r]);
    }
}

// ---------------------------------------------------------------- launch
extern "C" void kernel_launch(void* const* d_in, const int* in_sizes, int n_in,
                              void* d_out, int out_size, void* d_ws, size_t ws_size,
                              hipStream_t stream) {
  const int*   positions = (const int*)d_in[0];
  const float* hs = (const float*)d_in[1];
  const float* wq = (const float*)d_in[2];
  const float* wk = (const float*)d_in[3];
  const float* wv = (const float*)d_in[4];
  const float* wo = (const float*)d_in[5];
  float* out = (float*)d_out;

  const size_t SZ_WT = (size_t)HID * HID * 2;
  const size_t SZ_HB = (size_t)T_SEQ * HID * 2;
  const size_t SZ_QB = (size_t)T_SEQ * NQH * HDIM * 2;
  const size_t SZ_KB = (size_t)T_SEQ * NKVH * HDIM * 2;
  const size_t need = SZ_WT + SZ_HB + SZ_QB + SZ_KB * 2;
  if (ws_size < need) return;  // absmax 4.625 signature

  char* p = (char*)d_ws;
  unsigned short* wt  = (unsigned short*)p; p += SZ_WT;
  unsigned short* hb  = (unsigned short*)p; p += SZ_HB;
  unsigned short* qb  = (unsigned short*)p; p += SZ_QB;
  unsigned short* kb  = (unsigned short*)p; p += SZ_KB;
  unsigned short* vtb = (unsigned short*)p; p += SZ_KB;
  unsigned short* ab  = hb;  // alias: hb dead after KV-GEMM

  conv_f32_bf16<<<(T_SEQ * HID) / 1024, 256, 0, stream>>>(hs, hb);

  // Q projection
  transpose_conv<<<dim3((NQH * HDIM) / 64, HID / 64), 256, 0, stream>>>(wq, wt, HID, NQH * HDIM);
  gemm_bt<0><<<dim3((NQH * HDIM) / 128, T_SEQ / 128), 256, 0, stream>>>(hb, wt, qb, T_SEQ, NQH * HDIM, HID);

  // K + V projection fused (N = 2048), BM=64
  transpose_conv_kv<<<dim3((NKVH * HDIM) / 64, HID / 64, 2), 256, 0, stream>>>(wk, wv, wt);
  gemm_kv64<<<dim3(16, 32), 256, 0, stream>>>(hb, wt, kb, vtb);

  rope_all<<<(T_SEQ * (NQH + NKVH)) / 4, 256, 0, stream>>>(qb, kb, positions);

  attn_kernel<<<dim3(32, 32), 256, 0, stream>>>(qb, kb, vtb, ab);

  // output projection
  transpose_conv<<<dim3(HID / 64, (NQH * HDIM) / 64), 256, 0, stream>>>(wo, wt, NQH * HDIM, HID);
  gemm_bt<2><<<dim3(HID / 128, T_SEQ / 128), 256, 0, stream>>>(ab, wt, out, T_SEQ, HID, NQH * HDIM);
}